// Round 5
// baseline (2563.532 us; speedup 1.0000x reference)
//
#include <hip/hip_runtime.h>
#include <math.h>

#define NFEAT 256
#define HID 64
#define NCLS 6
#define NREP 32                 // counter/region replicas (replica = blockIdx&31 -> fixed XCD)
#define SUBCAP 128              // per-replica capacity (mean fill 64, sd 8)
#define CAP (NREP * SUBCAP)     // 4096 entries per bucket (mean 2048)
#define PAD 68                  // LDS accumulator row stride (floats); 68%32=4 staggers banks

// ---------------- utility ----------------

__global__ __launch_bounds__(256) void k_zero_int(int* __restrict__ p, int n) {
  int i = blockIdx.x * 256 + threadIdx.x;
  if (i < n) p[i] = 0;
}

// ---------------- bucket pass: group edges by dst>>6, 32-way replicated ----------------
// packed entry = (src << 6) | (dst & 63); src < 2^17 fits.

__global__ __launch_bounds__(256) void k_bucket(const int* __restrict__ src,
                                                const int* __restrict__ dst,
                                                int* __restrict__ bcur,
                                                unsigned* __restrict__ packed,
                                                int E, int nbuck) {
  int i = blockIdx.x * 256 + threadIdx.x;
  if (i >= E) return;
  int r = blockIdx.x & (NREP - 1);
  int d = dst[i], s = src[i];
  int b = d >> 6;
  int p = atomicAdd(&bcur[r * nbuck + b], 1);
  if (p >= SUBCAP) p = SUBCAP - 1;  // statistically unreachable (8 sd)
  packed[((size_t)b * NREP + r) * SUBCAP + p] = ((unsigned)s << 6) | (unsigned)(d & 63);
}

// ---------------- per-bucket degree -> dis ----------------

__global__ __launch_bounds__(256) void k_disb(const unsigned* __restrict__ packed,
                                              const int* __restrict__ bcur,
                                              float* __restrict__ dis,
                                              int n, int nbuck) {
  __shared__ int cntl[64];
  __shared__ int mr[NREP];
  int b = blockIdx.x;
  int t = threadIdx.x;
  if (t < 64) cntl[t] = 0;
  if (t < NREP) {
    int c = bcur[t * nbuck + b];
    mr[t] = (c > SUBCAP) ? SUBCAP : c;
  }
  __syncthreads();
  const unsigned* pb = packed + (size_t)b * CAP;
  for (int k = t; k < CAP; k += 256) {
    int r = k >> 7;            // /SUBCAP
    int p = k & (SUBCAP - 1);
    if (p < mr[r]) atomicAdd(&cntl[pb[k] & 63u], 1);
  }
  __syncthreads();
  if (t < 64) {
    int v = b * 64 + t;
    if (v < n) dis[v] = rsqrtf((float)cntl[t] + 1.0f);  // +1 self-loop
  }
}

// ---------------- GEMM: G[row] = dis[row] * (X[row,:] @ W), W is K x 64 ----------------

template<int K>
__global__ __launch_bounds__(256) void k_gemm_scaled(const float* __restrict__ X,
                                                     const float* __restrict__ W,
                                                     const float* __restrict__ dis,
                                                     float* __restrict__ G, int n) {
  __shared__ float Wl[64 * 64];
  __shared__ float Xl[64 * 64];
  const int tid = threadIdx.x;
  const int row0 = blockIdx.x * 64;
  const int tc = tid & 15;
  const int tr = tid >> 4;
  float acc[4][4] = {};

  for (int k0 = 0; k0 < K; k0 += 64) {
    __syncthreads();
#pragma unroll
    for (int i = 0; i < 4; ++i) {
      int idx = tid * 4 + i * 1024;
      int kr = idx >> 6, c = idx & 63;
      *(float4*)&Wl[idx] = *(const float4*)&W[(size_t)(k0 + kr) * 64 + c];
    }
#pragma unroll
    for (int i = 0; i < 4; ++i) {
      int idx = tid * 4 + i * 1024;
      int r = idx >> 6, c = idx & 63;
      int row = row0 + r;
      float4 v = make_float4(0.f, 0.f, 0.f, 0.f);
      if (row < n) v = *(const float4*)&X[(size_t)row * K + k0 + c];
      *(float4*)&Xl[idx] = v;
    }
    __syncthreads();
#pragma unroll 4
    for (int kk = 0; kk < 64; kk += 4) {
      float4 xv[4], wv[4];
#pragma unroll
      for (int r = 0; r < 4; ++r) xv[r] = *(float4*)&Xl[(tr * 4 + r) * 64 + kk];
#pragma unroll
      for (int q = 0; q < 4; ++q) wv[q] = *(float4*)&Wl[(kk + q) * 64 + tc * 4];
#pragma unroll
      for (int r = 0; r < 4; ++r) {
        const float xr[4] = {xv[r].x, xv[r].y, xv[r].z, xv[r].w};
#pragma unroll
        for (int q = 0; q < 4; ++q) {
          acc[r][0] += xr[q] * wv[q].x;
          acc[r][1] += xr[q] * wv[q].y;
          acc[r][2] += xr[q] * wv[q].z;
          acc[r][3] += xr[q] * wv[q].w;
        }
      }
    }
  }
#pragma unroll
  for (int r = 0; r < 4; ++r) {
    int row = row0 + tr * 4 + r;
    if (row < n) {
      float s = dis[row];
      float4 o = make_float4(acc[r][0] * s, acc[r][1] * s, acc[r][2] * s, acc[r][3] * s);
      *(float4*)&G[(size_t)row * 64 + tc * 4] = o;
    }
  }
}

// ---------------- fused bucket aggregation + finalize ----------------
// One block per bucket (64 dst nodes). LDS accumulator [64][PAD].
// out[v] = relu(dis[v] * (sum_{s in N(v)} g[s] + g[v]) + b)

__global__ __launch_bounds__(256) void k_agg_fused(const unsigned* __restrict__ packed,
                                                   const int* __restrict__ bcur,
                                                   const float* __restrict__ g,
                                                   const float* __restrict__ dis,
                                                   const float* __restrict__ bias,
                                                   float* __restrict__ outp,
                                                   int n, int nbuck) {
  __shared__ float accl[64 * PAD];
  __shared__ int mr[NREP];
  int b = blockIdx.x;
  int t = threadIdx.x;
  for (int i = t; i < 64 * PAD; i += 256) accl[i] = 0.f;
  if (t < NREP) {
    int c = bcur[t * nbuck + b];
    mr[t] = (c > SUBCAP) ? SUBCAP : c;
  }
  __syncthreads();

  const unsigned* pb = packed + (size_t)b * CAP;
  const float4* g4 = (const float4*)g;
  int grp = t >> 4;        // 0..15
  int lane = t & 15;

  // each 16-lane group drains replicas 2*grp and 2*grp+1
#pragma unroll
  for (int rq = 0; rq < 2; ++rq) {
    int rr = grp * 2 + rq;
    const uint4* pr4 = (const uint4*)(pb + rr * SUBCAP);
    int m = mr[rr];
    int k = 0;
    for (; k + 4 <= m; k += 4) {
      uint4 e = pr4[k >> 2];
      float4 a0 = g4[(size_t)(e.x >> 6) * 16 + lane];
      float4 a1 = g4[(size_t)(e.y >> 6) * 16 + lane];
      float4 a2 = g4[(size_t)(e.z >> 6) * 16 + lane];
      float4 a3 = g4[(size_t)(e.w >> 6) * 16 + lane];
      float* p0 = &accl[(e.x & 63u) * PAD + lane * 4];
      float* p1 = &accl[(e.y & 63u) * PAD + lane * 4];
      float* p2 = &accl[(e.z & 63u) * PAD + lane * 4];
      float* p3 = &accl[(e.w & 63u) * PAD + lane * 4];
      atomicAdd(p0 + 0, a0.x); atomicAdd(p0 + 1, a0.y); atomicAdd(p0 + 2, a0.z); atomicAdd(p0 + 3, a0.w);
      atomicAdd(p1 + 0, a1.x); atomicAdd(p1 + 1, a1.y); atomicAdd(p1 + 2, a1.z); atomicAdd(p1 + 3, a1.w);
      atomicAdd(p2 + 0, a2.x); atomicAdd(p2 + 1, a2.y); atomicAdd(p2 + 2, a2.z); atomicAdd(p2 + 3, a2.w);
      atomicAdd(p3 + 0, a3.x); atomicAdd(p3 + 1, a3.y); atomicAdd(p3 + 2, a3.z); atomicAdd(p3 + 3, a3.w);
    }
    const unsigned* pr = pb + rr * SUBCAP;
    for (; k < m; ++k) {
      unsigned e0 = pr[k];
      float4 a0 = g4[(size_t)(e0 >> 6) * 16 + lane];
      float* p0 = &accl[(e0 & 63u) * PAD + lane * 4];
      atomicAdd(p0 + 0, a0.x); atomicAdd(p0 + 1, a0.y); atomicAdd(p0 + 2, a0.z); atomicAdd(p0 + 3, a0.w);
    }
  }
  __syncthreads();

  // epilogue: each group finalizes rows grp, grp+16, grp+32, grp+48
  for (int r = grp; r < 64; r += 16) {
    int v = b * 64 + r;
    if (v >= n) break;
    float dv = dis[v];
    float4 s = g4[(size_t)v * 16 + lane];
    float4 a = *(float4*)&accl[r * PAD + lane * 4];
    float4 bb = *(const float4*)&bias[lane * 4];
    float4 o;
    o.x = fmaxf(fmaf(dv, a.x + s.x, bb.x), 0.f);
    o.y = fmaxf(fmaf(dv, a.y + s.y, bb.y), 0.f);
    o.z = fmaxf(fmaf(dv, a.z + s.z, bb.z), 0.f);
    o.w = fmaxf(fmaf(dv, a.w + s.w, bb.w), 0.f);
    ((float4*)outp)[(size_t)v * 16 + lane] = o;
  }
}

// ---------------- final FC: out[row] = A[row,:] @ Wfc + bfc ----------------

__global__ __launch_bounds__(256) void k_fc(const float* __restrict__ A,
                                            const float* __restrict__ Wfc,
                                            const float* __restrict__ bfc,
                                            float* __restrict__ outp, int n) {
  __shared__ float Wl[64 * NCLS];
  __shared__ float bl[8];
  int tid = threadIdx.x;
  for (int i = tid; i < 64 * NCLS; i += 256) Wl[i] = Wfc[i];
  if (tid < NCLS) bl[tid] = bfc[tid];
  __syncthreads();
  int row = blockIdx.x * 256 + tid;
  if (row >= n) return;
  float accv[NCLS];
#pragma unroll
  for (int j = 0; j < NCLS; ++j) accv[j] = bl[j];
  const float4* a4 = (const float4*)&A[(size_t)row * 64];
#pragma unroll
  for (int k4 = 0; k4 < 16; ++k4) {
    float4 a = a4[k4];
    const float av[4] = {a.x, a.y, a.z, a.w};
#pragma unroll
    for (int q = 0; q < 4; ++q)
#pragma unroll
      for (int j = 0; j < NCLS; ++j) accv[j] += av[q] * Wl[(k4 * 4 + q) * NCLS + j];
  }
#pragma unroll
  for (int j = 0; j < NCLS; ++j) outp[(size_t)row * NCLS + j] = accv[j];
}

// ---------------- launch ----------------

extern "C" void kernel_launch(void* const* d_in, const int* in_sizes, int n_in,
                              void* d_out, int out_size, void* d_ws, size_t ws_size,
                              hipStream_t stream) {
  const float* x   = (const float*)d_in[0];
  const int*   ei  = (const int*)d_in[1];
  const float* W1  = (const float*)d_in[2];
  const float* b1  = (const float*)d_in[3];
  const float* W2  = (const float*)d_in[4];
  const float* b2  = (const float*)d_in[5];
  const float* Wfc = (const float*)d_in[6];
  const float* bfc = (const float*)d_in[7];
  float* out = (float*)d_out;

  const int n = in_sizes[0] / NFEAT;   // 100000
  const int E = in_sizes[1] / 2;       // 3200000
  const int* src = ei;
  const int* dst = ei + E;
  const int nbuck = (n + 63) >> 6;     // 1563

  char* ws = (char*)d_ws;
  size_t off = 0;
  auto alloc = [&](size_t bytes) -> void* {
    void* p = (void*)(ws + off);
    off += (bytes + 255) & ~(size_t)255;
    return p;
  };
  float*    dis    = (float*)alloc((size_t)n * 4);
  int*      bcur   = (int*)alloc((size_t)nbuck * NREP * 4);
  unsigned* packed = (unsigned*)alloc((size_t)nbuck * CAP * 4);  // 25.6 MB, persistent
  float*    bufA   = (float*)alloc((size_t)n * HID * 4);
  float*    bufB   = (float*)alloc((size_t)n * HID * 4);

  // ---- bucket build (shared by both layers) ----
  k_zero_int<<<(nbuck * NREP + 255) / 256, 256, 0, stream>>>(bcur, nbuck * NREP);
  k_bucket<<<(E + 255) / 256, 256, 0, stream>>>(src, dst, bcur, packed, E, nbuck);
  k_disb<<<nbuck, 256, 0, stream>>>(packed, bcur, dis, n, nbuck);

  // ---- layer 1 ----
  k_gemm_scaled<NFEAT><<<(n + 63) / 64, 256, 0, stream>>>(x, W1, dis, bufA, n);
  k_agg_fused<<<nbuck, 256, 0, stream>>>(packed, bcur, bufA, dis, b1, bufB, n, nbuck);

  // ---- layer 2 ----
  k_gemm_scaled<HID><<<(n + 63) / 64, 256, 0, stream>>>(bufB, W2, dis, bufA, n);
  k_agg_fused<<<nbuck, 256, 0, stream>>>(packed, bcur, bufA, dis, b2, bufB, n, nbuck);

  // ---- FC head ----
  k_fc<<<(n + 255) / 256, 256, 0, stream>>>(bufB, Wfc, bfc, out, n);
}

// Round 6
// 460.068 us; speedup vs baseline: 5.5721x; 5.5721x over previous
//
#include <hip/hip_runtime.h>
#include <math.h>

#define NFEAT 256
#define HID 64
#define NCLS 6
#define NREP 32                 // counter/region replicas (replica = blockIdx&31 -> fixed XCD)
#define SUBCAP 128              // per-replica capacity (mean fill 64, sd 8)
#define CAP (NREP * SUBCAP)     // 4096 entries per bucket (mean 2048)
#define SEGSHIFT 13             // src segment = src>>13 (8192 nodes = 2MB of g), 16 segs max
#define NSEG 16
#define NBIN (64 * NSEG)        // counting-sort bins: (dst&63)<<4 | seg

// ---------------- utility ----------------

__global__ __launch_bounds__(256) void k_zero_int(int* __restrict__ p, int n) {
  int i = blockIdx.x * 256 + threadIdx.x;
  if (i < n) p[i] = 0;
}

// ---------------- bucket pass: group edges by dst>>6, 32-way replicated ----------------
// packed entry = (src << 6) | (dst & 63); src < 2^17 fits.

__global__ __launch_bounds__(256) void k_bucket(const int* __restrict__ src,
                                                const int* __restrict__ dst,
                                                int* __restrict__ bcur,
                                                unsigned* __restrict__ packed,
                                                int E, int nbuck) {
  int i = blockIdx.x * 256 + threadIdx.x;
  if (i >= E) return;
  int r = blockIdx.x & (NREP - 1);
  int d = dst[i], s = src[i];
  int b = d >> 6;
  int p = atomicAdd(&bcur[r * nbuck + b], 1);
  if (p >= SUBCAP) p = SUBCAP - 1;  // statistically unreachable (8 sd)
  packed[((size_t)b * NREP + r) * SUBCAP + p] = ((unsigned)s << 6) | (unsigned)(d & 63);
}

// ---------------- scan per-bucket totals -> bucket bases; rowptr[n] = E ----------------

__global__ __launch_bounds__(256) void k_scanb(const int* __restrict__ bcur,
                                               int* __restrict__ bbase, int nb,
                                               int* __restrict__ rowptr_n) {
  __shared__ int sh[256];
  __shared__ int carry;
  int t = threadIdx.x;
  if (t == 0) carry = 0;
  __syncthreads();
  for (int base = 0; base < nb; base += 256) {
    int v = 0;
    if (base + t < nb) {
#pragma unroll 8
      for (int r = 0; r < NREP; ++r) {
        int c = bcur[r * nb + base + t];
        v += (c > SUBCAP) ? SUBCAP : c;
      }
    }
    sh[t] = v;
    __syncthreads();
    for (int off = 1; off < 256; off <<= 1) {
      int x = sh[t];
      int y = (t >= off) ? sh[t - off] : 0;
      __syncthreads();
      sh[t] = x + y;
      __syncthreads();
    }
    if (base + t < nb) bbase[base + t] = carry + sh[t] - v;
    __syncthreads();
    if (t == 255) carry += sh[255];
    __syncthreads();
  }
  if (t == 0) *rowptr_n = carry;
}

// ---------------- per-bucket counting sort by (row, src-seg) -> srcs, rowptr, dis ----------------
// one block per bucket (64 nodes); srcs written sequentially, grouped by src segment
// within each row so the agg kernel's gathers walk monotone ~2MB windows.

__global__ __launch_bounds__(256) void k_build(const unsigned* __restrict__ packed,
                                               const int* __restrict__ bcur,
                                               const int* __restrict__ bbase,
                                               int* __restrict__ rowptr,
                                               int* __restrict__ srcs,
                                               float* __restrict__ dis,
                                               int n, int nbuck) {
  __shared__ int cnt[NBIN];
  __shared__ int offx[NBIN];
  __shared__ int tsum[256];
  __shared__ int mr[NREP];
  int b = blockIdx.x;
  int t = threadIdx.x;
  if (t < NREP) {
    int c = bcur[t * nbuck + b];
    mr[t] = (c > SUBCAP) ? SUBCAP : c;
  }
#pragma unroll
  for (int i = 0; i < 4; ++i) cnt[t * 4 + i] = 0;
  __syncthreads();
  const unsigned* pb = packed + (size_t)b * CAP;

  // histogram over (row, seg)
  for (int k = t; k < CAP; k += 256) {
    int r = k >> 7, p = k & (SUBCAP - 1);
    if (p < mr[r]) {
      unsigned e = pb[k];
      int bin = ((e & 63u) << 4) | ((e >> 6) >> SEGSHIFT);
      atomicAdd(&cnt[bin], 1);
    }
  }
  __syncthreads();
  // block scan: thread t owns bins 4t..4t+3
  int c4[4], partial = 0;
#pragma unroll
  for (int i = 0; i < 4; ++i) { c4[i] = cnt[t * 4 + i]; partial += c4[i]; }
  tsum[t] = partial;
  __syncthreads();
  for (int off = 1; off < 256; off <<= 1) {
    int x = tsum[t];
    int y = (t >= off) ? tsum[t - off] : 0;
    __syncthreads();
    tsum[t] = x + y;
    __syncthreads();
  }
  int run = tsum[t] - partial;
#pragma unroll
  for (int i = 0; i < 4; ++i) {
    offx[t * 4 + i] = run;
    run += c4[i];
    cnt[t * 4 + i] = 0;  // reuse as scatter cursor
  }
  __syncthreads();
  int bb = bbase[b];
  int tot = tsum[255];
  if (t < 64) {
    int v = b * 64 + t;
    if (v < n) {
      int beg = offx[t * 16];
      int end = (t == 63) ? tot : offx[(t + 1) * 16];
      rowptr[v] = bb + beg;
      dis[v] = rsqrtf((float)(end - beg) + 1.0f);  // +1 self-loop
    }
  }
  __syncthreads();
  // scatter
  for (int k = t; k < CAP; k += 256) {
    int r = k >> 7, p = k & (SUBCAP - 1);
    if (p < mr[r]) {
      unsigned e = pb[k];
      int bin = ((e & 63u) << 4) | ((e >> 6) >> SEGSHIFT);
      int q = atomicAdd(&cnt[bin], 1);
      srcs[bb + offx[bin] + q] = (int)(e >> 6);
    }
  }
}

// ---------------- GEMM: G[row] = dis[row] * (X[row,:] @ W), W is K x 64 ----------------

template<int K>
__global__ __launch_bounds__(256) void k_gemm_scaled(const float* __restrict__ X,
                                                     const float* __restrict__ W,
                                                     const float* __restrict__ dis,
                                                     float* __restrict__ G, int n) {
  __shared__ float Wl[64 * 64];
  __shared__ float Xl[64 * 64];
  const int tid = threadIdx.x;
  const int row0 = blockIdx.x * 64;
  const int tc = tid & 15;
  const int tr = tid >> 4;
  float acc[4][4] = {};

  for (int k0 = 0; k0 < K; k0 += 64) {
    __syncthreads();
#pragma unroll
    for (int i = 0; i < 4; ++i) {
      int idx = tid * 4 + i * 1024;
      int kr = idx >> 6, c = idx & 63;
      *(float4*)&Wl[idx] = *(const float4*)&W[(size_t)(k0 + kr) * 64 + c];
    }
#pragma unroll
    for (int i = 0; i < 4; ++i) {
      int idx = tid * 4 + i * 1024;
      int r = idx >> 6, c = idx & 63;
      int row = row0 + r;
      float4 v = make_float4(0.f, 0.f, 0.f, 0.f);
      if (row < n) v = *(const float4*)&X[(size_t)row * K + k0 + c];
      *(float4*)&Xl[idx] = v;
    }
    __syncthreads();
#pragma unroll 4
    for (int kk = 0; kk < 64; kk += 4) {
      float4 xv[4], wv[4];
#pragma unroll
      for (int r = 0; r < 4; ++r) xv[r] = *(float4*)&Xl[(tr * 4 + r) * 64 + kk];
#pragma unroll
      for (int q = 0; q < 4; ++q) wv[q] = *(float4*)&Wl[(kk + q) * 64 + tc * 4];
#pragma unroll
      for (int r = 0; r < 4; ++r) {
        const float xr[4] = {xv[r].x, xv[r].y, xv[r].z, xv[r].w};
#pragma unroll
        for (int q = 0; q < 4; ++q) {
          acc[r][0] += xr[q] * wv[q].x;
          acc[r][1] += xr[q] * wv[q].y;
          acc[r][2] += xr[q] * wv[q].z;
          acc[r][3] += xr[q] * wv[q].w;
        }
      }
    }
  }
#pragma unroll
  for (int r = 0; r < 4; ++r) {
    int row = row0 + tr * 4 + r;
    if (row < n) {
      float s = dis[row];
      float4 o = make_float4(acc[r][0] * s, acc[r][1] * s, acc[r][2] * s, acc[r][3] * s);
      *(float4*)&G[(size_t)row * 64 + tc * 4] = o;
    }
  }
}

// ---------------- CSR gather-sum + fused finalize ----------------
// out[v] = relu(dis[v] * (sum_{s in N(v)} g[s] + g[v]) + b)
// srcs per row are seg-grouped -> concurrent gathers share a sliding L2 window.

__global__ __launch_bounds__(256) void k_agg_csr(const int* __restrict__ rowptr,
                                                 const int* __restrict__ srcs,
                                                 const float* __restrict__ g,
                                                 const float* __restrict__ dis,
                                                 const float* __restrict__ bias,
                                                 float* __restrict__ outp, int n) {
  int v = blockIdx.x * 16 + (threadIdx.x >> 4);
  if (v >= n) return;
  int lane = threadIdx.x & 15;
  int beg = rowptr[v], end = rowptr[v + 1];
  const float4* g4 = (const float4*)g;
  float4 self = g4[(size_t)v * 16 + lane];
  float ax = self.x, ay = self.y, az = self.z, aw = self.w;

  int j = beg;
  for (; j + 8 <= end; j += 8) {
    int s[8];
#pragma unroll
    for (int q = 0; q < 8; ++q) s[q] = srcs[j + q];
    float4 a[8];
#pragma unroll
    for (int q = 0; q < 8; ++q) a[q] = g4[(size_t)s[q] * 16 + lane];
#pragma unroll
    for (int q = 0; q < 8; ++q) {
      ax += a[q].x; ay += a[q].y; az += a[q].z; aw += a[q].w;
    }
  }
  for (; j + 4 <= end; j += 4) {
    int s0 = srcs[j], s1 = srcs[j + 1], s2 = srcs[j + 2], s3 = srcs[j + 3];
    float4 a0 = g4[(size_t)s0 * 16 + lane];
    float4 a1 = g4[(size_t)s1 * 16 + lane];
    float4 a2 = g4[(size_t)s2 * 16 + lane];
    float4 a3 = g4[(size_t)s3 * 16 + lane];
    ax += a0.x + a1.x + a2.x + a3.x;
    ay += a0.y + a1.y + a2.y + a3.y;
    az += a0.z + a1.z + a2.z + a3.z;
    aw += a0.w + a1.w + a2.w + a3.w;
  }
  for (; j < end; ++j) {
    int s0 = srcs[j];
    float4 a0 = g4[(size_t)s0 * 16 + lane];
    ax += a0.x; ay += a0.y; az += a0.z; aw += a0.w;
  }

  float dv = dis[v];
  float4 bb = *(const float4*)&bias[lane * 4];
  float4 o;
  o.x = fmaxf(fmaf(dv, ax, bb.x), 0.f);
  o.y = fmaxf(fmaf(dv, ay, bb.y), 0.f);
  o.z = fmaxf(fmaf(dv, az, bb.z), 0.f);
  o.w = fmaxf(fmaf(dv, aw, bb.w), 0.f);
  ((float4*)outp)[(size_t)v * 16 + lane] = o;
}

// ---------------- final FC: out[row] = A[row,:] @ Wfc + bfc ----------------

__global__ __launch_bounds__(256) void k_fc(const float* __restrict__ A,
                                            const float* __restrict__ Wfc,
                                            const float* __restrict__ bfc,
                                            float* __restrict__ outp, int n) {
  __shared__ float Wl[64 * NCLS];
  __shared__ float bl[8];
  int tid = threadIdx.x;
  for (int i = tid; i < 64 * NCLS; i += 256) Wl[i] = Wfc[i];
  if (tid < NCLS) bl[tid] = bfc[tid];
  __syncthreads();
  int row = blockIdx.x * 256 + tid;
  if (row >= n) return;
  float accv[NCLS];
#pragma unroll
  for (int j = 0; j < NCLS; ++j) accv[j] = bl[j];
  const float4* a4 = (const float4*)&A[(size_t)row * 64];
#pragma unroll
  for (int k4 = 0; k4 < 16; ++k4) {
    float4 a = a4[k4];
    const float av[4] = {a.x, a.y, a.z, a.w};
#pragma unroll
    for (int q = 0; q < 4; ++q)
#pragma unroll
      for (int j = 0; j < NCLS; ++j) accv[j] += av[q] * Wl[(k4 * 4 + q) * NCLS + j];
  }
#pragma unroll
  for (int j = 0; j < NCLS; ++j) outp[(size_t)row * NCLS + j] = accv[j];
}

// ---------------- launch ----------------

extern "C" void kernel_launch(void* const* d_in, const int* in_sizes, int n_in,
                              void* d_out, int out_size, void* d_ws, size_t ws_size,
                              hipStream_t stream) {
  const float* x   = (const float*)d_in[0];
  const int*   ei  = (const int*)d_in[1];
  const float* W1  = (const float*)d_in[2];
  const float* b1  = (const float*)d_in[3];
  const float* W2  = (const float*)d_in[4];
  const float* b2  = (const float*)d_in[5];
  const float* Wfc = (const float*)d_in[6];
  const float* bfc = (const float*)d_in[7];
  float* out = (float*)d_out;

  const int n = in_sizes[0] / NFEAT;   // 100000
  const int E = in_sizes[1] / 2;       // 3200000
  const int* src = ei;
  const int* dst = ei + E;
  const int nbuck = (n + 63) >> 6;     // 1563

  char* ws = (char*)d_ws;
  size_t off = 0;
  auto alloc = [&](size_t bytes) -> void* {
    void* p = (void*)(ws + off);
    off += (bytes + 255) & ~(size_t)255;
    return p;
  };
  float* dis    = (float*)alloc((size_t)n * 4);
  int*   rowptr = (int*)alloc(((size_t)n + 1) * 4);
  int*   srcs   = (int*)alloc((size_t)E * 4);
  int*   bcur   = (int*)alloc((size_t)nbuck * NREP * 4);
  int*   bbase  = (int*)alloc((size_t)nbuck * 4);
  // region shared by packed-bucket buffer (build phase) and bufA (layer phase)
  size_t sharedBytes = (size_t)nbuck * CAP * 4;  // 25.6 MB >= n*HID*4
  if ((size_t)n * HID * 4 > sharedBytes) sharedBytes = (size_t)n * HID * 4;
  unsigned* packed = (unsigned*)alloc(sharedBytes);
  float* bufA = (float*)packed;
  float* bufB = (float*)alloc((size_t)n * HID * 4);

  // ---- CSR build (shared by both layers) ----
  k_zero_int<<<(nbuck * NREP + 255) / 256, 256, 0, stream>>>(bcur, nbuck * NREP);
  k_bucket<<<(E + 255) / 256, 256, 0, stream>>>(src, dst, bcur, packed, E, nbuck);
  k_scanb<<<1, 256, 0, stream>>>(bcur, bbase, nbuck, rowptr + n);
  k_build<<<nbuck, 256, 0, stream>>>(packed, bcur, bbase, rowptr, srcs, dis, n, nbuck);

  // ---- layer 1 ----
  k_gemm_scaled<NFEAT><<<(n + 63) / 64, 256, 0, stream>>>(x, W1, dis, bufA, n);
  k_agg_csr<<<(n + 15) / 16, 256, 0, stream>>>(rowptr, srcs, bufA, dis, b1, bufB, n);

  // ---- layer 2 ----
  k_gemm_scaled<HID><<<(n + 63) / 64, 256, 0, stream>>>(bufB, W2, dis, bufA, n);
  k_agg_csr<<<(n + 15) / 16, 256, 0, stream>>>(rowptr, srcs, bufA, dis, b2, bufB, n);

  // ---- FC head ----
  k_fc<<<(n + 255) / 256, 256, 0, stream>>>(bufB, Wfc, bfc, out, n);
}

// Round 7
// 394.120 us; speedup vs baseline: 6.5044x; 1.1673x over previous
//
#include <hip/hip_runtime.h>
#include <hip/hip_fp16.h>
#include <math.h>

#define NFEAT 256
#define HID 64
#define NCLS 6
#define NREP 32                 // replicas; replica = blockIdx&31 -> fixed XCD
#define SUBCAP 128              // per-replica capacity (mean fill 64, sd 8)
#define CAP (NREP * SUBCAP)     // 4096 entries per bucket (mean 2048)

typedef float vf4 __attribute__((ext_vector_type(4)));

// ---------------- utility ----------------

__global__ __launch_bounds__(256) void k_zero_int(int* __restrict__ p, int n) {
  int i = blockIdx.x * 256 + threadIdx.x;
  if (i < n) p[i] = 0;
}

// ---------------- bucket pass: 4 edges/thread, NT edge loads ----------------
// packed entry = (src << 6) | (dst & 63); src < 2^17 fits.

__global__ __launch_bounds__(256) void k_bucket(const int* __restrict__ src,
                                                const int* __restrict__ dst,
                                                int* __restrict__ bcur,
                                                unsigned* __restrict__ packed,
                                                int E, int nbuck) {
  int base = (blockIdx.x * 256 + threadIdx.x) * 4;
  int r = blockIdx.x & (NREP - 1);
  int rb = r * nbuck;
  int s[4], d[4], p[4];
#pragma unroll
  for (int q = 0; q < 4; ++q) {
    int i = base + q;
    if (i < E) {
      s[q] = __builtin_nontemporal_load(&src[i]);
      d[q] = __builtin_nontemporal_load(&dst[i]);
    }
  }
#pragma unroll
  for (int q = 0; q < 4; ++q) {
    int i = base + q;
    if (i < E) {
      p[q] = atomicAdd(&bcur[rb + (d[q] >> 6)], 1);
      if (p[q] >= SUBCAP) p[q] = SUBCAP - 1;  // statistically unreachable (8 sd)
    }
  }
#pragma unroll
  for (int q = 0; q < 4; ++q) {
    int i = base + q;
    if (i < E) {
      int b = d[q] >> 6;
      packed[((size_t)b * NREP + r) * SUBCAP + p[q]] =
          ((unsigned)s[q] << 6) | (unsigned)(d[q] & 63);
    }
  }
}

// ---------------- scan per-bucket totals -> bucket bases ----------------

__global__ __launch_bounds__(256) void k_scanb(const int* __restrict__ bcur,
                                               int* __restrict__ bbase, int nb,
                                               int* __restrict__ rowptr_n) {
  __shared__ int sh[256];
  __shared__ int carry;
  int t = threadIdx.x;
  if (t == 0) carry = 0;
  __syncthreads();
  for (int base = 0; base < nb; base += 256) {
    int v = 0;
    if (base + t < nb) {
#pragma unroll 8
      for (int r = 0; r < NREP; ++r) {
        int c = bcur[r * nb + base + t];
        v += (c > SUBCAP) ? SUBCAP : c;
      }
    }
    sh[t] = v;
    __syncthreads();
    for (int off = 1; off < 256; off <<= 1) {
      int x = sh[t];
      int y = (t >= off) ? sh[t - off] : 0;
      __syncthreads();
      sh[t] = x + y;
      __syncthreads();
    }
    if (base + t < nb) bbase[base + t] = carry + sh[t] - v;
    __syncthreads();
    if (t == 255) carry += sh[255];
    __syncthreads();
  }
  if (t == 0) *rowptr_n = carry;
}

// ---------------- per-bucket counting sort -> srcs, rowptr, dis ----------------

__global__ __launch_bounds__(256) void k_build(const unsigned* __restrict__ packed,
                                               const int* __restrict__ bcur,
                                               const int* __restrict__ bbase,
                                               int* __restrict__ rowptr,
                                               int* __restrict__ srcs,
                                               float* __restrict__ dis,
                                               int n, int nbuck) {
  __shared__ int cntl[64];
  __shared__ int offi[64];
  __shared__ int offx[64];
  __shared__ int cur[64];
  __shared__ int mr[NREP];
  int b = blockIdx.x;
  int t = threadIdx.x;
  if (t < NREP) {
    int c = bcur[t * nbuck + b];
    mr[t] = (c > SUBCAP) ? SUBCAP : c;
  }
  if (t < 64) { cntl[t] = 0; cur[t] = 0; }
  __syncthreads();
  const unsigned* pb = packed + (size_t)b * CAP;

  for (int k = t; k < CAP; k += 256) {
    int r = k >> 7, p = k & (SUBCAP - 1);
    if (p < mr[r]) atomicAdd(&cntl[pb[k] & 63u], 1);
  }
  __syncthreads();
  if (t < 64) offi[t] = cntl[t];
  __syncthreads();
  for (int off = 1; off < 64; off <<= 1) {
    int x = (t < 64) ? offi[t] : 0;
    int y = (t >= off && t < 64) ? offi[t - off] : 0;
    __syncthreads();
    if (t < 64) offi[t] = x + y;
    __syncthreads();
  }
  int bb = bbase[b];
  if (t < 64) {
    offx[t] = offi[t] - cntl[t];
    int v = b * 64 + t;
    if (v < n) {
      rowptr[v] = bb + offx[t];
      dis[v] = rsqrtf((float)cntl[t] + 1.0f);  // +1 self-loop
    }
  }
  __syncthreads();
  for (int k = t; k < CAP; k += 256) {
    int r = k >> 7, p = k & (SUBCAP - 1);
    if (p < mr[r]) {
      unsigned e = pb[k];
      int dl = e & 63u;
      int q = atomicAdd(&cur[dl], 1);
      srcs[bb + offx[dl] + q] = (int)(e >> 6);
    }
  }
}

// ---------------- GEMM: G16[row] = fp16(dis[row] * (X[row,:] @ W)), W is K x 64 ----------------

template<int K>
__global__ __launch_bounds__(256) void k_gemm_scaled(const float* __restrict__ X,
                                                     const float* __restrict__ W,
                                                     const float* __restrict__ dis,
                                                     __half* __restrict__ G16, int n) {
  __shared__ float Wl[64 * 64];
  __shared__ float Xl[64 * 64];
  const int tid = threadIdx.x;
  const int row0 = blockIdx.x * 64;
  const int tc = tid & 15;
  const int tr = tid >> 4;
  float acc[4][4] = {};

  for (int k0 = 0; k0 < K; k0 += 64) {
    __syncthreads();
#pragma unroll
    for (int i = 0; i < 4; ++i) {
      int idx = tid * 4 + i * 1024;
      int kr = idx >> 6, c = idx & 63;
      *(float4*)&Wl[idx] = *(const float4*)&W[(size_t)(k0 + kr) * 64 + c];
    }
#pragma unroll
    for (int i = 0; i < 4; ++i) {
      int idx = tid * 4 + i * 1024;
      int r = idx >> 6, c = idx & 63;
      int row = row0 + r;
      vf4 v = {0.f, 0.f, 0.f, 0.f};
      if (row < n) v = __builtin_nontemporal_load((const vf4*)&X[(size_t)row * K + k0 + c]);
      *(vf4*)&Xl[idx] = v;
    }
    __syncthreads();
#pragma unroll 4
    for (int kk = 0; kk < 64; kk += 4) {
      float4 xv[4], wv[4];
#pragma unroll
      for (int r = 0; r < 4; ++r) xv[r] = *(float4*)&Xl[(tr * 4 + r) * 64 + kk];
#pragma unroll
      for (int q = 0; q < 4; ++q) wv[q] = *(float4*)&Wl[(kk + q) * 64 + tc * 4];
#pragma unroll
      for (int r = 0; r < 4; ++r) {
        const float xr[4] = {xv[r].x, xv[r].y, xv[r].z, xv[r].w};
#pragma unroll
        for (int q = 0; q < 4; ++q) {
          acc[r][0] += xr[q] * wv[q].x;
          acc[r][1] += xr[q] * wv[q].y;
          acc[r][2] += xr[q] * wv[q].z;
          acc[r][3] += xr[q] * wv[q].w;
        }
      }
    }
  }
#pragma unroll
  for (int r = 0; r < 4; ++r) {
    int row = row0 + tr * 4 + r;
    if (row < n) {
      float s = dis[row];
      __half2 h01 = __floats2half2_rn(acc[r][0] * s, acc[r][1] * s);
      __half2 h23 = __floats2half2_rn(acc[r][2] * s, acc[r][3] * s);
      uint2 st;
      st.x = *reinterpret_cast<unsigned*>(&h01);
      st.y = *reinterpret_cast<unsigned*>(&h23);
      ((uint2*)G16)[(size_t)row * 16 + tc] = st;
    }
  }
}

// ---------------- CSR gather-sum (fp16 messages) + fused finalize ----------------
// out[v] = relu(dis[v] * (sum_{s in N(v)} g[s] + g[v]) + b)

__global__ __launch_bounds__(256) void k_agg_csr(const int* __restrict__ rowptr,
                                                 const int* __restrict__ srcs,
                                                 const __half* __restrict__ g16,
                                                 const float* __restrict__ dis,
                                                 const float* __restrict__ bias,
                                                 float* __restrict__ outp, int n) {
  int v = blockIdx.x * 16 + (threadIdx.x >> 4);
  if (v >= n) return;
  int lane = threadIdx.x & 15;
  int beg = rowptr[v], end = rowptr[v + 1];
  const uint2* g2 = (const uint2*)g16;  // row = 16 uint2 (64 halfs)

  uint2 su = g2[(size_t)v * 16 + lane];
  float2 f0 = __half22float2(*reinterpret_cast<__half2*>(&su.x));
  float2 f1 = __half22float2(*reinterpret_cast<__half2*>(&su.y));
  float ax = f0.x, ay = f0.y, az = f1.x, aw = f1.y;

  int j = beg;
  for (; j + 8 <= end; j += 8) {
    int s[8];
#pragma unroll
    for (int q = 0; q < 8; ++q) s[q] = __builtin_nontemporal_load(&srcs[j + q]);
    uint2 a[8];
#pragma unroll
    for (int q = 0; q < 8; ++q) a[q] = g2[(size_t)s[q] * 16 + lane];
#pragma unroll
    for (int q = 0; q < 8; ++q) {
      float2 p0 = __half22float2(*reinterpret_cast<__half2*>(&a[q].x));
      float2 p1 = __half22float2(*reinterpret_cast<__half2*>(&a[q].y));
      ax += p0.x; ay += p0.y; az += p1.x; aw += p1.y;
    }
  }
  for (; j < end; ++j) {
    int s0 = __builtin_nontemporal_load(&srcs[j]);
    uint2 a0 = g2[(size_t)s0 * 16 + lane];
    float2 p0 = __half22float2(*reinterpret_cast<__half2*>(&a0.x));
    float2 p1 = __half22float2(*reinterpret_cast<__half2*>(&a0.y));
    ax += p0.x; ay += p0.y; az += p1.x; aw += p1.y;
  }

  float dv = dis[v];
  float4 bb = *(const float4*)&bias[lane * 4];
  float4 o;
  o.x = fmaxf(fmaf(dv, ax, bb.x), 0.f);
  o.y = fmaxf(fmaf(dv, ay, bb.y), 0.f);
  o.z = fmaxf(fmaf(dv, az, bb.z), 0.f);
  o.w = fmaxf(fmaf(dv, aw, bb.w), 0.f);
  ((float4*)outp)[(size_t)v * 16 + lane] = o;
}

// ---------------- final FC: out[row] = A[row,:] @ Wfc + bfc ----------------

__global__ __launch_bounds__(256) void k_fc(const float* __restrict__ A,
                                            const float* __restrict__ Wfc,
                                            const float* __restrict__ bfc,
                                            float* __restrict__ outp, int n) {
  __shared__ float Wl[64 * NCLS];
  __shared__ float bl[8];
  int tid = threadIdx.x;
  for (int i = tid; i < 64 * NCLS; i += 256) Wl[i] = Wfc[i];
  if (tid < NCLS) bl[tid] = bfc[tid];
  __syncthreads();
  int row = blockIdx.x * 256 + tid;
  if (row >= n) return;
  float accv[NCLS];
#pragma unroll
  for (int j = 0; j < NCLS; ++j) accv[j] = bl[j];
  const vf4* a4 = (const vf4*)&A[(size_t)row * 64];
#pragma unroll
  for (int k4 = 0; k4 < 16; ++k4) {
    vf4 a = __builtin_nontemporal_load(&a4[k4]);
    const float av[4] = {a.x, a.y, a.z, a.w};
#pragma unroll
    for (int q = 0; q < 4; ++q)
#pragma unroll
      for (int j = 0; j < NCLS; ++j) accv[j] += av[q] * Wl[(k4 * 4 + q) * NCLS + j];
  }
#pragma unroll
  for (int j = 0; j < NCLS; ++j) outp[(size_t)row * NCLS + j] = accv[j];
}

// ---------------- launch ----------------

extern "C" void kernel_launch(void* const* d_in, const int* in_sizes, int n_in,
                              void* d_out, int out_size, void* d_ws, size_t ws_size,
                              hipStream_t stream) {
  const float* x   = (const float*)d_in[0];
  const int*   ei  = (const int*)d_in[1];
  const float* W1  = (const float*)d_in[2];
  const float* b1  = (const float*)d_in[3];
  const float* W2  = (const float*)d_in[4];
  const float* b2  = (const float*)d_in[5];
  const float* Wfc = (const float*)d_in[6];
  const float* bfc = (const float*)d_in[7];
  float* out = (float*)d_out;

  const int n = in_sizes[0] / NFEAT;   // 100000
  const int E = in_sizes[1] / 2;       // 3200000
  const int* src = ei;
  const int* dst = ei + E;
  const int nbuck = (n + 63) >> 6;     // 1563

  char* ws = (char*)d_ws;
  size_t off = 0;
  auto alloc = [&](size_t bytes) -> void* {
    void* p = (void*)(ws + off);
    off += (bytes + 255) & ~(size_t)255;
    return p;
  };
  float* dis    = (float*)alloc((size_t)n * 4);
  int*   rowptr = (int*)alloc(((size_t)n + 1) * 4);
  int*   srcs   = (int*)alloc((size_t)E * 4);
  int*   bcur   = (int*)alloc((size_t)nbuck * NREP * 4);
  int*   bbase  = (int*)alloc((size_t)nbuck * 4);
  // region shared by packed-bucket buffer (build phase) and bufA16 (layer phase)
  size_t sharedBytes = (size_t)nbuck * CAP * 4;  // 25.6 MB >= n*HID*2
  unsigned* packed = (unsigned*)alloc(sharedBytes);
  __half* bufA16 = (__half*)packed;              // 12.8 MB used
  float* bufB = (float*)alloc((size_t)n * HID * 4);

  // ---- CSR build (shared by both layers) ----
  k_zero_int<<<(nbuck * NREP + 255) / 256, 256, 0, stream>>>(bcur, nbuck * NREP);
  k_bucket<<<(E + 1023) / 1024, 256, 0, stream>>>(src, dst, bcur, packed, E, nbuck);
  k_scanb<<<1, 256, 0, stream>>>(bcur, bbase, nbuck, rowptr + n);
  k_build<<<nbuck, 256, 0, stream>>>(packed, bcur, bbase, rowptr, srcs, dis, n, nbuck);

  // ---- layer 1 ----
  k_gemm_scaled<NFEAT><<<(n + 63) / 64, 256, 0, stream>>>(x, W1, dis, bufA16, n);
  k_agg_csr<<<(n + 15) / 16, 256, 0, stream>>>(rowptr, srcs, bufA16, dis, b1, bufB, n);

  // ---- layer 2 ----
  k_gemm_scaled<HID><<<(n + 63) / 64, 256, 0, stream>>>(bufB, W2, dis, bufA16, n);
  k_agg_csr<<<(n + 15) / 16, 256, 0, stream>>>(rowptr, srcs, bufA16, dis, b2, bufB, n);

  // ---- FC head ----
  k_fc<<<(n + 255) / 256, 256, 0, stream>>>(bufB, Wfc, bfc, out, n);
}

// Round 10
// 355.335 us; speedup vs baseline: 7.2144x; 1.1091x over previous
//
#include <hip/hip_runtime.h>
#include <hip/hip_fp16.h>
#include <math.h>

#define NFEAT 256
#define HID 64
#define NCLS 6
#define CAP 4096        // per-bucket packed region (mean fill 2048, Poisson tail << CAP)
#define NBMX 1600       // LDS array sizing (nbuck = 1563 for n = 100000)
#define RCAP 8          // LDS granule entries per bucket (32 B)
#define CHUNK 16384     // edges per block
#define ROUND 1024      // edges per round (4 per thread)

typedef float vf4 __attribute__((ext_vector_type(4)));
typedef int   vi4 __attribute__((ext_vector_type(4)));

// ---------------- utility ----------------

__global__ __launch_bounds__(256) void k_zero_int(int* __restrict__ p, int n) {
  int i = blockIdx.x * 256 + threadIdx.x;
  if (i < n) p[i] = 0;
}

// ---------------- LDS-staged binning: group edges by dst>>6 ----------------
// packed entry = (src << 6) | (dst & 63). Full-granule flushes -> dense writes.
// Overflow (slot >= RCAP) falls back to a lossless direct global write.

__global__ __launch_bounds__(256) void k_binpack(const int* __restrict__ src,
                                                 const int* __restrict__ dst,
                                                 int* __restrict__ gcur,
                                                 unsigned* __restrict__ packed,
                                                 int E, int nbuck) {
  __shared__ unsigned ring[NBMX * RCAP];   // 51.2 KB
  __shared__ int basel[NBMX];              // 6.4 KB
  int t = threadIdx.x;
  for (int i = t; i < nbuck; i += 256) basel[i] = 0;
  __syncthreads();

  int e0 = blockIdx.x * CHUNK;
  int e1 = e0 + CHUNK;
  if (e1 > E) e1 = E;

  for (int r0 = e0; r0 < e1; r0 += ROUND) {
    int i0 = r0 + t * 4;
    int s4[4], d4[4];
    bool full = (i0 + 4 <= e1);
    if (full) {
      vi4 sv = __builtin_nontemporal_load((const vi4*)&src[i0]);
      vi4 dv = __builtin_nontemporal_load((const vi4*)&dst[i0]);
      s4[0] = sv.x; s4[1] = sv.y; s4[2] = sv.z; s4[3] = sv.w;
      d4[0] = dv.x; d4[1] = dv.y; d4[2] = dv.z; d4[3] = dv.w;
    } else {
      for (int q = 0; q < 4; ++q)
        if (i0 + q < e1) { s4[q] = src[i0 + q]; d4[q] = dst[i0 + q]; }
    }
#pragma unroll
    for (int q = 0; q < 4; ++q) {
      if (i0 + q < e1) {
        int b = d4[q] >> 6;
        unsigned e = ((unsigned)s4[q] << 6) | (unsigned)(d4[q] & 63);
        int sl = atomicAdd(&basel[b], 1);
        if (sl < RCAP) ring[b * RCAP + sl] = e;
        else packed[(size_t)b * CAP + atomicAdd(&gcur[b], 1)] = e;  // lossless fallback
      }
    }
    __syncthreads();
    // flush full granules (dense, temporally-clustered stores)
    for (int b = t; b < nbuck; b += 256) {
      if (basel[b] >= RCAP) {
        int gb = atomicAdd(&gcur[b], RCAP);
        unsigned* pd = &packed[(size_t)b * CAP + gb];
#pragma unroll
        for (int k = 0; k < RCAP; ++k) pd[k] = ring[b * RCAP + k];
        basel[b] = 0;
      }
    }
    __syncthreads();
  }
  // residual flush
  for (int b = t; b < nbuck; b += 256) {
    int m = basel[b];
    if (m > 0) {
      int gb = atomicAdd(&gcur[b], m);
      unsigned* pd = &packed[(size_t)b * CAP + gb];
      for (int k = 0; k < m; ++k) pd[k] = ring[b * RCAP + k];
    }
  }
}

// ---------------- scan per-bucket totals -> bucket bases ----------------

__global__ __launch_bounds__(256) void k_scanb(const int* __restrict__ gcur,
                                               int* __restrict__ bbase, int nb,
                                               int* __restrict__ rowptr_n) {
  __shared__ int sh[256];
  __shared__ int carry;
  int t = threadIdx.x;
  if (t == 0) carry = 0;
  __syncthreads();
  for (int base = 0; base < nb; base += 256) {
    int v = 0;
    if (base + t < nb) {
      int c = gcur[base + t];
      v = (c > CAP) ? CAP : c;
    }
    sh[t] = v;
    __syncthreads();
    for (int off = 1; off < 256; off <<= 1) {
      int x = sh[t];
      int y = (t >= off) ? sh[t - off] : 0;
      __syncthreads();
      sh[t] = x + y;
      __syncthreads();
    }
    if (base + t < nb) bbase[base + t] = carry + sh[t] - v;
    __syncthreads();
    if (t == 255) carry += sh[255];
    __syncthreads();
  }
  if (t == 0) *rowptr_n = carry;
}

// ---------------- per-bucket counting sort -> srcs, rowptr, dis ----------------
// packed regions are dense: iterate m entries contiguously.

__global__ __launch_bounds__(256) void k_build(const unsigned* __restrict__ packed,
                                               const int* __restrict__ gcur,
                                               const int* __restrict__ bbase,
                                               int* __restrict__ rowptr,
                                               int* __restrict__ srcs,
                                               float* __restrict__ dis,
                                               int n, int nbuck) {
  __shared__ int cntl[64];
  __shared__ int offi[64];
  __shared__ int offx[64];
  __shared__ int cur[64];
  int b = blockIdx.x;
  int t = threadIdx.x;
  int m = gcur[b];
  if (m > CAP) m = CAP;
  if (t < 64) { cntl[t] = 0; cur[t] = 0; }
  __syncthreads();
  const unsigned* pb = packed + (size_t)b * CAP;

  for (int k = t; k < m; k += 256)
    atomicAdd(&cntl[__builtin_nontemporal_load(&pb[k]) & 63u], 1);
  __syncthreads();
  if (t < 64) offi[t] = cntl[t];
  __syncthreads();
  for (int off = 1; off < 64; off <<= 1) {
    int x = (t < 64) ? offi[t] : 0;
    int y = (t >= off && t < 64) ? offi[t - off] : 0;
    __syncthreads();
    if (t < 64) offi[t] = x + y;
    __syncthreads();
  }
  int bb = bbase[b];
  if (t < 64) {
    offx[t] = offi[t] - cntl[t];
    int v = b * 64 + t;
    if (v < n) {
      rowptr[v] = bb + offx[t];
      dis[v] = rsqrtf((float)cntl[t] + 1.0f);  // +1 self-loop
    }
  }
  __syncthreads();
  for (int k = t; k < m; k += 256) {
    unsigned e = pb[k];
    int dl = e & 63u;
    int q = atomicAdd(&cur[dl], 1);
    srcs[bb + offx[dl] + q] = (int)(e >> 6);
  }
}

// ---------------- GEMM: G16[row] = fp16(dis[row] * (X[row,:] @ W)), W is K x 64 ----------------

template<int K>
__global__ __launch_bounds__(256) void k_gemm_scaled(const float* __restrict__ X,
                                                     const float* __restrict__ W,
                                                     const float* __restrict__ dis,
                                                     __half* __restrict__ G16, int n) {
  __shared__ float Wl[64 * 64];
  __shared__ float Xl[64 * 64];
  const int tid = threadIdx.x;
  const int row0 = blockIdx.x * 64;
  const int tc = tid & 15;
  const int tr = tid >> 4;
  float acc[4][4] = {};

  for (int k0 = 0; k0 < K; k0 += 64) {
    __syncthreads();
#pragma unroll
    for (int i = 0; i < 4; ++i) {
      int idx = tid * 4 + i * 1024;
      int kr = idx >> 6, c = idx & 63;
      *(float4*)&Wl[idx] = *(const float4*)&W[(size_t)(k0 + kr) * 64 + c];
    }
#pragma unroll
    for (int i = 0; i < 4; ++i) {
      int idx = tid * 4 + i * 1024;
      int r = idx >> 6, c = idx & 63;
      int row = row0 + r;
      vf4 v = {0.f, 0.f, 0.f, 0.f};
      if (row < n) v = __builtin_nontemporal_load((const vf4*)&X[(size_t)row * K + k0 + c]);
      *(vf4*)&Xl[idx] = v;
    }
    __syncthreads();
#pragma unroll 4
    for (int kk = 0; kk < 64; kk += 4) {
      float4 xv[4], wv[4];
#pragma unroll
      for (int r = 0; r < 4; ++r) xv[r] = *(float4*)&Xl[(tr * 4 + r) * 64 + kk];
#pragma unroll
      for (int q = 0; q < 4; ++q) wv[q] = *(float4*)&Wl[(kk + q) * 64 + tc * 4];
#pragma unroll
      for (int r = 0; r < 4; ++r) {
        const float xr[4] = {xv[r].x, xv[r].y, xv[r].z, xv[r].w};
#pragma unroll
        for (int q = 0; q < 4; ++q) {
          acc[r][0] += xr[q] * wv[q].x;
          acc[r][1] += xr[q] * wv[q].y;
          acc[r][2] += xr[q] * wv[q].z;
          acc[r][3] += xr[q] * wv[q].w;
        }
      }
    }
  }
#pragma unroll
  for (int r = 0; r < 4; ++r) {
    int row = row0 + tr * 4 + r;
    if (row < n) {
      float s = dis[row];
      __half2 h01 = __floats2half2_rn(acc[r][0] * s, acc[r][1] * s);
      __half2 h23 = __floats2half2_rn(acc[r][2] * s, acc[r][3] * s);
      uint2 st;
      st.x = *reinterpret_cast<unsigned*>(&h01);
      st.y = *reinterpret_cast<unsigned*>(&h23);
      ((uint2*)G16)[(size_t)row * 16 + tc] = st;
    }
  }
}

// ---------------- CSR gather-sum (fp16 messages) + fused finalize ----------------
// out[v] = relu(dis[v] * (sum_{s in N(v)} g[s] + g[v]) + b)

__global__ __launch_bounds__(256) void k_agg_csr(const int* __restrict__ rowptr,
                                                 const int* __restrict__ srcs,
                                                 const __half* __restrict__ g16,
                                                 const float* __restrict__ dis,
                                                 const float* __restrict__ bias,
                                                 float* __restrict__ outp, int n) {
  int v = blockIdx.x * 16 + (threadIdx.x >> 4);
  if (v >= n) return;
  int lane = threadIdx.x & 15;
  int beg = rowptr[v], end = rowptr[v + 1];
  const uint2* g2 = (const uint2*)g16;  // row = 16 uint2 (64 halfs)

  uint2 su = g2[(size_t)v * 16 + lane];
  float2 f0 = __half22float2(*reinterpret_cast<__half2*>(&su.x));
  float2 f1 = __half22float2(*reinterpret_cast<__half2*>(&su.y));
  float ax = f0.x, ay = f0.y, az = f1.x, aw = f1.y;

  int j = beg;
  for (; j + 8 <= end; j += 8) {
    int s[8];
#pragma unroll
    for (int q = 0; q < 8; ++q) s[q] = __builtin_nontemporal_load(&srcs[j + q]);
    uint2 a[8];
#pragma unroll
    for (int q = 0; q < 8; ++q) a[q] = g2[(size_t)s[q] * 16 + lane];
#pragma unroll
    for (int q = 0; q < 8; ++q) {
      float2 p0 = __half22float2(*reinterpret_cast<__half2*>(&a[q].x));
      float2 p1 = __half22float2(*reinterpret_cast<__half2*>(&a[q].y));
      ax += p0.x; ay += p0.y; az += p1.x; aw += p1.y;
    }
  }
  for (; j < end; ++j) {
    int s0 = __builtin_nontemporal_load(&srcs[j]);
    uint2 a0 = g2[(size_t)s0 * 16 + lane];
    float2 p0 = __half22float2(*reinterpret_cast<__half2*>(&a0.x));
    float2 p1 = __half22float2(*reinterpret_cast<__half2*>(&a0.y));
    ax += p0.x; ay += p0.y; az += p1.x; aw += p1.y;
  }

  float dv = dis[v];
  float4 bb = *(const float4*)&bias[lane * 4];
  float4 o;
  o.x = fmaxf(fmaf(dv, ax, bb.x), 0.f);
  o.y = fmaxf(fmaf(dv, ay, bb.y), 0.f);
  o.z = fmaxf(fmaf(dv, az, bb.z), 0.f);
  o.w = fmaxf(fmaf(dv, aw, bb.w), 0.f);
  ((float4*)outp)[(size_t)v * 16 + lane] = o;
}

// ---------------- final FC: out[row] = A[row,:] @ Wfc + bfc ----------------

__global__ __launch_bounds__(256) void k_fc(const float* __restrict__ A,
                                            const float* __restrict__ Wfc,
                                            const float* __restrict__ bfc,
                                            float* __restrict__ outp, int n) {
  __shared__ float Wl[64 * NCLS];
  __shared__ float bl[8];
  int tid = threadIdx.x;
  for (int i = tid; i < 64 * NCLS; i += 256) Wl[i] = Wfc[i];
  if (tid < NCLS) bl[tid] = bfc[tid];
  __syncthreads();
  int row = blockIdx.x * 256 + tid;
  if (row >= n) return;
  float accv[NCLS];
#pragma unroll
  for (int j = 0; j < NCLS; ++j) accv[j] = bl[j];
  const vf4* a4 = (const vf4*)&A[(size_t)row * 64];
#pragma unroll
  for (int k4 = 0; k4 < 16; ++k4) {
    vf4 a = __builtin_nontemporal_load(&a4[k4]);
    const float av[4] = {a.x, a.y, a.z, a.w};
#pragma unroll
    for (int q = 0; q < 4; ++q)
#pragma unroll
      for (int j = 0; j < NCLS; ++j) accv[j] += av[q] * Wl[(k4 * 4 + q) * NCLS + j];
  }
#pragma unroll
  for (int j = 0; j < NCLS; ++j) outp[(size_t)row * NCLS + j] = accv[j];
}

// ---------------- launch ----------------

extern "C" void kernel_launch(void* const* d_in, const int* in_sizes, int n_in,
                              void* d_out, int out_size, void* d_ws, size_t ws_size,
                              hipStream_t stream) {
  const float* x   = (const float*)d_in[0];
  const int*   ei  = (const int*)d_in[1];
  const float* W1  = (const float*)d_in[2];
  const float* b1  = (const float*)d_in[3];
  const float* W2  = (const float*)d_in[4];
  const float* b2  = (const float*)d_in[5];
  const float* Wfc = (const float*)d_in[6];
  const float* bfc = (const float*)d_in[7];
  float* out = (float*)d_out;

  const int n = in_sizes[0] / NFEAT;   // 100000
  const int E = in_sizes[1] / 2;       // 3200000
  const int* src = ei;
  const int* dst = ei + E;
  const int nbuck = (n + 63) >> 6;     // 1563 (<= NBMX)

  char* ws = (char*)d_ws;
  size_t off = 0;
  auto alloc = [&](size_t bytes) -> void* {
    void* p = (void*)(ws + off);
    off += (bytes + 255) & ~(size_t)255;
    return p;
  };
  float* dis    = (float*)alloc((size_t)n * 4);
  int*   rowptr = (int*)alloc(((size_t)n + 1) * 4);
  int*   srcs   = (int*)alloc((size_t)E * 4);
  int*   gcur   = (int*)alloc((size_t)nbuck * 4);
  int*   bbase  = (int*)alloc((size_t)nbuck * 4);
  // region shared by packed-bucket buffer (build phase) and bufA16 (layer phase)
  size_t sharedBytes = (size_t)nbuck * CAP * 4;  // 25.6 MB >= n*HID*2
  unsigned* packed = (unsigned*)alloc(sharedBytes);
  __half* bufA16 = (__half*)packed;              // 12.8 MB used
  float* bufB = (float*)alloc((size_t)n * HID * 4);

  // ---- CSR build (shared by both layers) ----
  k_zero_int<<<(nbuck + 255) / 256, 256, 0, stream>>>(gcur, nbuck);
  k_binpack<<<(E + CHUNK - 1) / CHUNK, 256, 0, stream>>>(src, dst, gcur, packed, E, nbuck);
  k_scanb<<<1, 256, 0, stream>>>(gcur, bbase, nbuck, rowptr + n);
  k_build<<<nbuck, 256, 0, stream>>>(packed, gcur, bbase, rowptr, srcs, dis, n, nbuck);

  // ---- layer 1 ----
  k_gemm_scaled<NFEAT><<<(n + 63) / 64, 256, 0, stream>>>(x, W1, dis, bufA16, n);
  k_agg_csr<<<(n + 15) / 16, 256, 0, stream>>>(rowptr, srcs, bufA16, dis, b1, bufB, n);

  // ---- layer 2 ----
  k_gemm_scaled<HID><<<(n + 63) / 64, 256, 0, stream>>>(bufB, W2, dis, bufA16, n);
  k_agg_csr<<<(n + 15) / 16, 256, 0, stream>>>(rowptr, srcs, bufA16, dis, b2, bufB, n);

  // ---- FC head ----
  k_fc<<<(n + 255) / 256, 256, 0, stream>>>(bufB, Wfc, bfc, out, n);
}

// Round 11
// 354.238 us; speedup vs baseline: 7.2367x; 1.0031x over previous
//
#include <hip/hip_runtime.h>
#include <hip/hip_fp16.h>
#include <math.h>

#define NFEAT 256
#define HID 64
#define NCLS 6
#define CAP 4096        // per-bucket packed region (mean fill 2048, Poisson tail << CAP)
#define NBMX 1600       // LDS array sizing (nbuck = 1563 for n = 100000)
#define RCAP 8          // LDS granule entries per bucket (32 B)
#define CHUNK 16384     // edges per block
#define BT 1024         // binpack block threads (16 waves for latency hiding)
#define ROUND (BT * 4)  // edges per round (4 per thread)

typedef float vf4 __attribute__((ext_vector_type(4)));
typedef int   vi4 __attribute__((ext_vector_type(4)));

// ---------------- utility ----------------

__global__ __launch_bounds__(256) void k_zero_int(int* __restrict__ p, int n) {
  int i = blockIdx.x * 256 + threadIdx.x;
  if (i < n) p[i] = 0;
}

// ---------------- LDS-staged binning: group edges by dst>>6 ----------------
// packed entry = (src << 6) | (dst & 63). Full-granule flushes -> dense writes.
// Overflow (slot >= RCAP) falls back to a lossless direct global write.

__global__ __launch_bounds__(BT) void k_binpack(const int* __restrict__ src,
                                                const int* __restrict__ dst,
                                                int* __restrict__ gcur,
                                                unsigned* __restrict__ packed,
                                                int E, int nbuck) {
  __shared__ unsigned ring[NBMX * RCAP];   // 51.2 KB
  __shared__ int basel[NBMX];              // 6.4 KB
  int t = threadIdx.x;
  for (int i = t; i < nbuck; i += BT) basel[i] = 0;
  __syncthreads();

  int e0 = blockIdx.x * CHUNK;
  int e1 = e0 + CHUNK;
  if (e1 > E) e1 = E;

  for (int r0 = e0; r0 < e1; r0 += ROUND) {
    int i0 = r0 + t * 4;
    int s4[4], d4[4];
    bool full = (i0 + 4 <= e1);
    if (full) {
      vi4 sv = __builtin_nontemporal_load((const vi4*)&src[i0]);
      vi4 dv = __builtin_nontemporal_load((const vi4*)&dst[i0]);
      s4[0] = sv.x; s4[1] = sv.y; s4[2] = sv.z; s4[3] = sv.w;
      d4[0] = dv.x; d4[1] = dv.y; d4[2] = dv.z; d4[3] = dv.w;
    } else {
      for (int q = 0; q < 4; ++q)
        if (i0 + q < e1) { s4[q] = src[i0 + q]; d4[q] = dst[i0 + q]; }
    }
#pragma unroll
    for (int q = 0; q < 4; ++q) {
      if (i0 + q < e1) {
        int b = d4[q] >> 6;
        unsigned e = ((unsigned)s4[q] << 6) | (unsigned)(d4[q] & 63);
        int sl = atomicAdd(&basel[b], 1);
        if (sl < RCAP) ring[b * RCAP + sl] = e;
        else packed[(size_t)b * CAP + atomicAdd(&gcur[b], 1)] = e;  // lossless fallback
      }
    }
    __syncthreads();
    // flush full granules (dense, temporally-clustered stores)
    for (int b = t; b < nbuck; b += BT) {
      if (basel[b] >= RCAP) {
        int gb = atomicAdd(&gcur[b], RCAP);
        unsigned* pd = &packed[(size_t)b * CAP + gb];
#pragma unroll
        for (int k = 0; k < RCAP; ++k) pd[k] = ring[b * RCAP + k];
        basel[b] = 0;
      }
    }
    __syncthreads();
  }
  // residual flush
  for (int b = t; b < nbuck; b += BT) {
    int m = basel[b];
    if (m > 0) {
      int gb = atomicAdd(&gcur[b], m);
      unsigned* pd = &packed[(size_t)b * CAP + gb];
      for (int k = 0; k < m; ++k) pd[k] = ring[b * RCAP + k];
    }
  }
}

// ---------------- scan per-bucket totals -> bucket bases ----------------

__global__ __launch_bounds__(256) void k_scanb(const int* __restrict__ gcur,
                                               int* __restrict__ bbase, int nb,
                                               int* __restrict__ rowptr_n) {
  __shared__ int sh[256];
  __shared__ int carry;
  int t = threadIdx.x;
  if (t == 0) carry = 0;
  __syncthreads();
  for (int base = 0; base < nb; base += 256) {
    int v = 0;
    if (base + t < nb) {
      int c = gcur[base + t];
      v = (c > CAP) ? CAP : c;
    }
    sh[t] = v;
    __syncthreads();
    for (int off = 1; off < 256; off <<= 1) {
      int x = sh[t];
      int y = (t >= off) ? sh[t - off] : 0;
      __syncthreads();
      sh[t] = x + y;
      __syncthreads();
    }
    if (base + t < nb) bbase[base + t] = carry + sh[t] - v;
    __syncthreads();
    if (t == 255) carry += sh[255];
    __syncthreads();
  }
  if (t == 0) *rowptr_n = carry;
}

// ---------------- per-bucket counting sort -> srcs, rowptr, dis ----------------
// 4 wave-group sub-histograms + pre-partitioned cursors to cut LDS atomic serialization.

__global__ __launch_bounds__(256) void k_build(const unsigned* __restrict__ packed,
                                               const int* __restrict__ gcur,
                                               const int* __restrict__ bbase,
                                               int* __restrict__ rowptr,
                                               int* __restrict__ srcs,
                                               float* __restrict__ dis,
                                               int n, int nbuck) {
  __shared__ int cnt4[4][64];
  __shared__ int cur4[4][64];
  __shared__ int offx[64];
  __shared__ int offi[64];
  __shared__ int cntl[64];
  int b = blockIdx.x;
  int t = threadIdx.x;
  int g = t >> 6;
  int m = gcur[b];
  if (m > CAP) m = CAP;
#pragma unroll
  for (int i = 0; i < 1; ++i) cnt4[g][t & 63] = 0;
  __syncthreads();
  const unsigned* pb = packed + (size_t)b * CAP;

  // per-group histogram (entry k handled by thread k%256, group (k%256)>>6)
  for (int k = t; k < m; k += 256)
    atomicAdd(&cnt4[g][__builtin_nontemporal_load(&pb[k]) & 63u], 1);
  __syncthreads();
  if (t < 64) {
    int c0 = cnt4[0][t], c1 = cnt4[1][t], c2 = cnt4[2][t], c3 = cnt4[3][t];
    int tot = c0 + c1 + c2 + c3;
    cntl[t] = tot;
    offi[t] = tot;
    // per-group bases within this bin (exclusive prefix over groups)
    cur4[0][t] = 0;
    cur4[1][t] = c0;
    cur4[2][t] = c0 + c1;
    cur4[3][t] = c0 + c1 + c2;
  }
  __syncthreads();
  for (int off = 1; off < 64; off <<= 1) {
    int x = (t < 64) ? offi[t] : 0;
    int y = (t >= off && t < 64) ? offi[t - off] : 0;
    __syncthreads();
    if (t < 64) offi[t] = x + y;
    __syncthreads();
  }
  int bb = bbase[b];
  if (t < 64) {
    offx[t] = offi[t] - cntl[t];
    int v = b * 64 + t;
    if (v < n) {
      rowptr[v] = bb + offx[t];
      dis[v] = rsqrtf((float)cntl[t] + 1.0f);  // +1 self-loop
    }
  }
  __syncthreads();
  if (t < 64) {
#pragma unroll
    for (int gg = 0; gg < 4; ++gg) cur4[gg][t] += offx[t];
  }
  __syncthreads();
  for (int k = t; k < m; k += 256) {
    unsigned e = pb[k];
    int dl = e & 63u;
    int q = atomicAdd(&cur4[g][dl], 1);
    srcs[bb + q] = (int)(e >> 6);
  }
}

// ---------------- GEMM: G16[row] = fp16(dis[row] * (X[row,:] @ W)), W is K x 64 ----------------

template<int K>
__global__ __launch_bounds__(256) void k_gemm_scaled(const float* __restrict__ X,
                                                     const float* __restrict__ W,
                                                     const float* __restrict__ dis,
                                                     __half* __restrict__ G16, int n) {
  __shared__ float Wl[64 * 64];
  __shared__ float Xl[64 * 64];
  const int tid = threadIdx.x;
  const int row0 = blockIdx.x * 64;
  const int tc = tid & 15;
  const int tr = tid >> 4;
  float acc[4][4] = {};

  for (int k0 = 0; k0 < K; k0 += 64) {
    __syncthreads();
#pragma unroll
    for (int i = 0; i < 4; ++i) {
      int idx = tid * 4 + i * 1024;
      int kr = idx >> 6, c = idx & 63;
      *(float4*)&Wl[idx] = *(const float4*)&W[(size_t)(k0 + kr) * 64 + c];
    }
#pragma unroll
    for (int i = 0; i < 4; ++i) {
      int idx = tid * 4 + i * 1024;
      int r = idx >> 6, c = idx & 63;
      int row = row0 + r;
      vf4 v = {0.f, 0.f, 0.f, 0.f};
      if (row < n) v = __builtin_nontemporal_load((const vf4*)&X[(size_t)row * K + k0 + c]);
      *(vf4*)&Xl[idx] = v;
    }
    __syncthreads();
#pragma unroll 4
    for (int kk = 0; kk < 64; kk += 4) {
      float4 xv[4], wv[4];
#pragma unroll
      for (int r = 0; r < 4; ++r) xv[r] = *(float4*)&Xl[(tr * 4 + r) * 64 + kk];
#pragma unroll
      for (int q = 0; q < 4; ++q) wv[q] = *(float4*)&Wl[(kk + q) * 64 + tc * 4];
#pragma unroll
      for (int r = 0; r < 4; ++r) {
        const float xr[4] = {xv[r].x, xv[r].y, xv[r].z, xv[r].w};
#pragma unroll
        for (int q = 0; q < 4; ++q) {
          acc[r][0] += xr[q] * wv[q].x;
          acc[r][1] += xr[q] * wv[q].y;
          acc[r][2] += xr[q] * wv[q].z;
          acc[r][3] += xr[q] * wv[q].w;
        }
      }
    }
  }
#pragma unroll
  for (int r = 0; r < 4; ++r) {
    int row = row0 + tr * 4 + r;
    if (row < n) {
      float s = dis[row];
      __half2 h01 = __floats2half2_rn(acc[r][0] * s, acc[r][1] * s);
      __half2 h23 = __floats2half2_rn(acc[r][2] * s, acc[r][3] * s);
      uint2 st;
      st.x = *reinterpret_cast<unsigned*>(&h01);
      st.y = *reinterpret_cast<unsigned*>(&h23);
      ((uint2*)G16)[(size_t)row * 16 + tc] = st;
    }
  }
}

// ---------------- CSR gather-sum (fp16 messages) + fused finalize ----------------
// out[v] = relu(dis[v] * (sum_{s in N(v)} g[s] + g[v]) + b)

__global__ __launch_bounds__(256) void k_agg_csr(const int* __restrict__ rowptr,
                                                 const int* __restrict__ srcs,
                                                 const __half* __restrict__ g16,
                                                 const float* __restrict__ dis,
                                                 const float* __restrict__ bias,
                                                 float* __restrict__ outp, int n) {
  int v = blockIdx.x * 16 + (threadIdx.x >> 4);
  if (v >= n) return;
  int lane = threadIdx.x & 15;
  int beg = rowptr[v], end = rowptr[v + 1];
  const uint2* g2 = (const uint2*)g16;  // row = 16 uint2 (64 halfs)

  uint2 su = g2[(size_t)v * 16 + lane];
  float2 f0 = __half22float2(*reinterpret_cast<__half2*>(&su.x));
  float2 f1 = __half22float2(*reinterpret_cast<__half2*>(&su.y));
  float ax = f0.x, ay = f0.y, az = f1.x, aw = f1.y;

  int j = beg;
  for (; j + 8 <= end; j += 8) {
    int s[8];
#pragma unroll
    for (int q = 0; q < 8; ++q) s[q] = __builtin_nontemporal_load(&srcs[j + q]);
    uint2 a[8];
#pragma unroll
    for (int q = 0; q < 8; ++q) a[q] = g2[(size_t)s[q] * 16 + lane];
#pragma unroll
    for (int q = 0; q < 8; ++q) {
      float2 p0 = __half22float2(*reinterpret_cast<__half2*>(&a[q].x));
      float2 p1 = __half22float2(*reinterpret_cast<__half2*>(&a[q].y));
      ax += p0.x; ay += p0.y; az += p1.x; aw += p1.y;
    }
  }
  for (; j < end; ++j) {
    int s0 = __builtin_nontemporal_load(&srcs[j]);
    uint2 a0 = g2[(size_t)s0 * 16 + lane];
    float2 p0 = __half22float2(*reinterpret_cast<__half2*>(&a0.x));
    float2 p1 = __half22float2(*reinterpret_cast<__half2*>(&a0.y));
    ax += p0.x; ay += p0.y; az += p1.x; aw += p1.y;
  }

  float dv = dis[v];
  float4 bb = *(const float4*)&bias[lane * 4];
  float4 o;
  o.x = fmaxf(fmaf(dv, ax, bb.x), 0.f);
  o.y = fmaxf(fmaf(dv, ay, bb.y), 0.f);
  o.z = fmaxf(fmaf(dv, az, bb.z), 0.f);
  o.w = fmaxf(fmaf(dv, aw, bb.w), 0.f);
  ((float4*)outp)[(size_t)v * 16 + lane] = o;
}

// ---------------- final FC: out[row] = A[row,:] @ Wfc + bfc ----------------

__global__ __launch_bounds__(256) void k_fc(const float* __restrict__ A,
                                            const float* __restrict__ Wfc,
                                            const float* __restrict__ bfc,
                                            float* __restrict__ outp, int n) {
  __shared__ float Wl[64 * NCLS];
  __shared__ float bl[8];
  int tid = threadIdx.x;
  for (int i = tid; i < 64 * NCLS; i += 256) Wl[i] = Wfc[i];
  if (tid < NCLS) bl[tid] = bfc[tid];
  __syncthreads();
  int row = blockIdx.x * 256 + tid;
  if (row >= n) return;
  float accv[NCLS];
#pragma unroll
  for (int j = 0; j < NCLS; ++j) accv[j] = bl[j];
  const vf4* a4 = (const vf4*)&A[(size_t)row * 64];
#pragma unroll
  for (int k4 = 0; k4 < 16; ++k4) {
    vf4 a = __builtin_nontemporal_load(&a4[k4]);
    const float av[4] = {a.x, a.y, a.z, a.w};
#pragma unroll
    for (int q = 0; q < 4; ++q)
#pragma unroll
      for (int j = 0; j < NCLS; ++j) accv[j] += av[q] * Wl[(k4 * 4 + q) * NCLS + j];
  }
#pragma unroll
  for (int j = 0; j < NCLS; ++j) outp[(size_t)row * NCLS + j] = accv[j];
}

// ---------------- launch ----------------

extern "C" void kernel_launch(void* const* d_in, const int* in_sizes, int n_in,
                              void* d_out, int out_size, void* d_ws, size_t ws_size,
                              hipStream_t stream) {
  const float* x   = (const float*)d_in[0];
  const int*   ei  = (const int*)d_in[1];
  const float* W1  = (const float*)d_in[2];
  const float* b1  = (const float*)d_in[3];
  const float* W2  = (const float*)d_in[4];
  const float* b2  = (const float*)d_in[5];
  const float* Wfc = (const float*)d_in[6];
  const float* bfc = (const float*)d_in[7];
  float* out = (float*)d_out;

  const int n = in_sizes[0] / NFEAT;   // 100000
  const int E = in_sizes[1] / 2;       // 3200000
  const int* src = ei;
  const int* dst = ei + E;
  const int nbuck = (n + 63) >> 6;     // 1563 (<= NBMX)

  char* ws = (char*)d_ws;
  size_t off = 0;
  auto alloc = [&](size_t bytes) -> void* {
    void* p = (void*)(ws + off);
    off += (bytes + 255) & ~(size_t)255;
    return p;
  };
  float* dis    = (float*)alloc((size_t)n * 4);
  int*   rowptr = (int*)alloc(((size_t)n + 1) * 4);
  int*   srcs   = (int*)alloc((size_t)E * 4);
  int*   gcur   = (int*)alloc((size_t)nbuck * 4);
  int*   bbase  = (int*)alloc((size_t)nbuck * 4);
  // region shared by packed-bucket buffer (build phase) and bufA16 (layer phase)
  size_t sharedBytes = (size_t)nbuck * CAP * 4;  // 25.6 MB >= n*HID*2
  unsigned* packed = (unsigned*)alloc(sharedBytes);
  __half* bufA16 = (__half*)packed;              // 12.8 MB used
  float* bufB = (float*)alloc((size_t)n * HID * 4);

  // ---- CSR build (shared by both layers) ----
  k_zero_int<<<(nbuck + 255) / 256, 256, 0, stream>>>(gcur, nbuck);
  k_binpack<<<(E + CHUNK - 1) / CHUNK, BT, 0, stream>>>(src, dst, gcur, packed, E, nbuck);
  k_scanb<<<1, 256, 0, stream>>>(gcur, bbase, nbuck, rowptr + n);
  k_build<<<nbuck, 256, 0, stream>>>(packed, gcur, bbase, rowptr, srcs, dis, n, nbuck);

  // ---- layer 1 ----
  k_gemm_scaled<NFEAT><<<(n + 63) / 64, 256, 0, stream>>>(x, W1, dis, bufA16, n);
  k_agg_csr<<<(n + 15) / 16, 256, 0, stream>>>(rowptr, srcs, bufA16, dis, b1, bufB, n);

  // ---- layer 2 ----
  k_gemm_scaled<HID><<<(n + 63) / 64, 256, 0, stream>>>(bufB, W2, dis, bufA16, n);
  k_agg_csr<<<(n + 15) / 16, 256, 0, stream>>>(rowptr, srcs, bufA16, dis, b2, bufB, n);

  // ---- FC head ----
  k_fc<<<(n + 255) / 256, 256, 0, stream>>>(bufB, Wfc, bfc, out, n);
}

// Round 12
// 319.786 us; speedup vs baseline: 8.0164x; 1.1077x over previous
//
#include <hip/hip_runtime.h>
#include <hip/hip_fp16.h>
#include <math.h>

#define NFEAT 256
#define HID 64
#define NCLS 6
#define CAP 4096        // per-bucket packed region (mean fill 2048)
#define NBMX 1600       // LDS sizing (nbuck = 1563)
#define RCAP 8          // LDS granule entries per bucket
#define CHUNK 16384     // edges per binpack block
#define ROUND 1024      // edges per round (4 per thread, 256 threads)
#define FUSED_LDS 57856 // max(binpack 57.6KB, gemm 32KB)

typedef float vf4 __attribute__((ext_vector_type(4)));
typedef int   vi4 __attribute__((ext_vector_type(4)));

// ---------------- utility ----------------

__global__ __launch_bounds__(256) void k_zero_int(int* __restrict__ p, int n) {
  int i = blockIdx.x * 256 + threadIdx.x;
  if (i < n) p[i] = 0;
}

// ---------------- FUSED: binpack (blocks < nbb)  ||  GEMM1 unscaled (blocks >= nbb) ----------------
// binpack: LDS-granule binning by dst>>6; packed entry = (src<<6)|(dst&63).
// gemm: H16[row] = fp16(X[row,:] @ W1)   (dis applied later in k_agg_w)

__global__ __launch_bounds__(256) void k_fused(const int* __restrict__ src,
                                               const int* __restrict__ dst,
                                               int* __restrict__ gcur,
                                               unsigned* __restrict__ packed,
                                               int E, int nbuck, int nbb,
                                               const float* __restrict__ X,
                                               const float* __restrict__ W1,
                                               __half* __restrict__ H16, int n) {
  extern __shared__ char smem[];
  int t = threadIdx.x;

  if (blockIdx.x < nbb) {
    // ---------------- binpack branch ----------------
    unsigned* ring = (unsigned*)smem;                 // NBMX*RCAP
    int* basel = (int*)(smem + NBMX * RCAP * 4);      // NBMX
    for (int i = t; i < nbuck; i += 256) basel[i] = 0;
    __syncthreads();

    int e0 = blockIdx.x * CHUNK;
    int e1 = e0 + CHUNK;
    if (e1 > E) e1 = E;

    for (int r0 = e0; r0 < e1; r0 += ROUND) {
      int i0 = r0 + t * 4;
      int s4[4], d4[4];
      bool full = (i0 + 4 <= e1);
      if (full) {
        vi4 sv = __builtin_nontemporal_load((const vi4*)&src[i0]);
        vi4 dv = __builtin_nontemporal_load((const vi4*)&dst[i0]);
        s4[0] = sv.x; s4[1] = sv.y; s4[2] = sv.z; s4[3] = sv.w;
        d4[0] = dv.x; d4[1] = dv.y; d4[2] = dv.z; d4[3] = dv.w;
      } else {
        for (int q = 0; q < 4; ++q)
          if (i0 + q < e1) { s4[q] = src[i0 + q]; d4[q] = dst[i0 + q]; }
      }
#pragma unroll
      for (int q = 0; q < 4; ++q) {
        if (i0 + q < e1) {
          int b = d4[q] >> 6;
          unsigned e = ((unsigned)s4[q] << 6) | (unsigned)(d4[q] & 63);
          int sl = atomicAdd(&basel[b], 1);
          if (sl < RCAP) ring[b * RCAP + sl] = e;
          else packed[(size_t)b * CAP + atomicAdd(&gcur[b], 1)] = e;  // lossless fallback
        }
      }
      __syncthreads();
      for (int b = t; b < nbuck; b += 256) {
        if (basel[b] >= RCAP) {
          int gb = atomicAdd(&gcur[b], RCAP);
          unsigned* pd = &packed[(size_t)b * CAP + gb];
#pragma unroll
          for (int k = 0; k < RCAP; ++k) pd[k] = ring[b * RCAP + k];
          basel[b] = 0;
        }
      }
      __syncthreads();
    }
    for (int b = t; b < nbuck; b += 256) {
      int m = basel[b];
      if (m > 0) {
        int gb = atomicAdd(&gcur[b], m);
        unsigned* pd = &packed[(size_t)b * CAP + gb];
        for (int k = 0; k < m; ++k) pd[k] = ring[b * RCAP + k];
      }
    }
  } else {
    // ---------------- gemm1 branch (K = NFEAT, unscaled fp16 out) ----------------
    float* Wl = (float*)smem;          // 64*64
    float* Xl = Wl + 4096;             // 64*64
    const int row0 = (blockIdx.x - nbb) * 64;
    const int tc = t & 15;
    const int tr = t >> 4;
    float acc[4][4] = {};

    for (int k0 = 0; k0 < NFEAT; k0 += 64) {
      __syncthreads();
#pragma unroll
      for (int i = 0; i < 4; ++i) {
        int idx = t * 4 + i * 1024;
        int kr = idx >> 6, c = idx & 63;
        *(vf4*)&Wl[idx] = *(const vf4*)&W1[(size_t)(k0 + kr) * 64 + c];
      }
#pragma unroll
      for (int i = 0; i < 4; ++i) {
        int idx = t * 4 + i * 1024;
        int r = idx >> 6, c = idx & 63;
        int row = row0 + r;
        vf4 v = {0.f, 0.f, 0.f, 0.f};
        if (row < n) v = __builtin_nontemporal_load((const vf4*)&X[(size_t)row * NFEAT + k0 + c]);
        *(vf4*)&Xl[idx] = v;
      }
      __syncthreads();
#pragma unroll 4
      for (int kk = 0; kk < 64; kk += 4) {
        float4 xv[4], wv[4];
#pragma unroll
        for (int r = 0; r < 4; ++r) xv[r] = *(float4*)&Xl[(tr * 4 + r) * 64 + kk];
#pragma unroll
        for (int q = 0; q < 4; ++q) wv[q] = *(float4*)&Wl[(kk + q) * 64 + tc * 4];
#pragma unroll
        for (int r = 0; r < 4; ++r) {
          const float xr[4] = {xv[r].x, xv[r].y, xv[r].z, xv[r].w};
#pragma unroll
          for (int q = 0; q < 4; ++q) {
            acc[r][0] += xr[q] * wv[q].x;
            acc[r][1] += xr[q] * wv[q].y;
            acc[r][2] += xr[q] * wv[q].z;
            acc[r][3] += xr[q] * wv[q].w;
          }
        }
      }
    }
#pragma unroll
    for (int r = 0; r < 4; ++r) {
      int row = row0 + tr * 4 + r;
      if (row < n) {
        __half2 h01 = __floats2half2_rn(acc[r][0], acc[r][1]);
        __half2 h23 = __floats2half2_rn(acc[r][2], acc[r][3]);
        uint2 st;
        st.x = *reinterpret_cast<unsigned*>(&h01);
        st.y = *reinterpret_cast<unsigned*>(&h23);
        ((uint2*)H16)[(size_t)row * 16 + tc] = st;
      }
    }
  }
}

// ---------------- build v2: in-LDS counting sort, in-place; emits rowrange + dis ----------------

__global__ __launch_bounds__(256) void k_build(unsigned* __restrict__ packed,
                                               const int* __restrict__ gcur,
                                               int2* __restrict__ rowrange,
                                               float* __restrict__ dis,
                                               int n, int nbuck) {
  __shared__ unsigned buf[CAP];   // 16KB
  __shared__ unsigned outb[CAP];  // 16KB
  __shared__ int cnt4[4][64];
  __shared__ int cur4[4][64];
  __shared__ int offi[64];
  __shared__ int offx[64];
  __shared__ int cntl[64];
  int b = blockIdx.x;
  int t = threadIdx.x;
  int g = t >> 6;
  int m = gcur[b];
  if (m > CAP) m = CAP;
  unsigned* pb = packed + (size_t)b * CAP;

  cnt4[g][t & 63] = 0;
  for (int k = t; k < m; k += 256) buf[k] = pb[k];
  __syncthreads();
  for (int k = t; k < m; k += 256) atomicAdd(&cnt4[g][buf[k] & 63u], 1);
  __syncthreads();
  if (t < 64) {
    int c0 = cnt4[0][t], c1 = cnt4[1][t], c2 = cnt4[2][t], c3 = cnt4[3][t];
    int tot = c0 + c1 + c2 + c3;
    cntl[t] = tot;
    offi[t] = tot;
    cur4[0][t] = 0;
    cur4[1][t] = c0;
    cur4[2][t] = c0 + c1;
    cur4[3][t] = c0 + c1 + c2;
  }
  __syncthreads();
  for (int off = 1; off < 64; off <<= 1) {
    int x = (t < 64) ? offi[t] : 0;
    int y = (t >= off && t < 64) ? offi[t - off] : 0;
    __syncthreads();
    if (t < 64) offi[t] = x + y;
    __syncthreads();
  }
  if (t < 64) {
    offx[t] = offi[t] - cntl[t];
    int v = b * 64 + t;
    if (v < n) {
      rowrange[v] = make_int2(b * CAP + offx[t], cntl[t]);
      dis[v] = rsqrtf((float)cntl[t] + 1.0f);  // +1 self-loop
    }
#pragma unroll
    for (int gg = 0; gg < 4; ++gg) cur4[gg][t] += offx[t];
  }
  __syncthreads();
  for (int k = t; k < m; k += 256) {
    unsigned e = buf[k];
    int dl = e & 63u;
    int q = atomicAdd(&cur4[g][dl], 1);
    outb[q] = e >> 6;
  }
  __syncthreads();
  for (int k = t; k < m; k += 256) pb[k] = outb[k];  // in place: packed becomes srcs
}

// ---------------- layer-1 agg: out = relu(dv*(sum dis[s]*h[s] + dv*h[v]) + b) ----------------

__global__ __launch_bounds__(256) void k_agg_w(const int2* __restrict__ rowrange,
                                               const int* __restrict__ srcs,
                                               const __half* __restrict__ g16,
                                               const float* __restrict__ dis,
                                               const float* __restrict__ bias,
                                               float* __restrict__ outp, int n) {
  int v = blockIdx.x * 16 + (threadIdx.x >> 4);
  if (v >= n) return;
  int lane = threadIdx.x & 15;
  int2 rr = rowrange[v];
  int j = rr.x, end = rr.x + rr.y;
  const uint2* g2 = (const uint2*)g16;

  float dv = dis[v];
  uint2 su = g2[(size_t)v * 16 + lane];
  float2 f0 = __half22float2(*reinterpret_cast<__half2*>(&su.x));
  float2 f1 = __half22float2(*reinterpret_cast<__half2*>(&su.y));
  float ax = dv * f0.x, ay = dv * f0.y, az = dv * f1.x, aw = dv * f1.y;

  for (; j + 8 <= end; j += 8) {
    int s[8];
#pragma unroll
    for (int q = 0; q < 8; ++q) s[q] = __builtin_nontemporal_load(&srcs[j + q]);
    float ds[8];
    uint2 a[8];
#pragma unroll
    for (int q = 0; q < 8; ++q) { ds[q] = dis[s[q]]; a[q] = g2[(size_t)s[q] * 16 + lane]; }
#pragma unroll
    for (int q = 0; q < 8; ++q) {
      float2 p0 = __half22float2(*reinterpret_cast<__half2*>(&a[q].x));
      float2 p1 = __half22float2(*reinterpret_cast<__half2*>(&a[q].y));
      ax = fmaf(ds[q], p0.x, ax); ay = fmaf(ds[q], p0.y, ay);
      az = fmaf(ds[q], p1.x, az); aw = fmaf(ds[q], p1.y, aw);
    }
  }
  for (; j < end; ++j) {
    int s0 = __builtin_nontemporal_load(&srcs[j]);
    float ds = dis[s0];
    uint2 a0 = g2[(size_t)s0 * 16 + lane];
    float2 p0 = __half22float2(*reinterpret_cast<__half2*>(&a0.x));
    float2 p1 = __half22float2(*reinterpret_cast<__half2*>(&a0.y));
    ax = fmaf(ds, p0.x, ax); ay = fmaf(ds, p0.y, ay);
    az = fmaf(ds, p1.x, az); aw = fmaf(ds, p1.y, aw);
  }

  float4 bb = *(const float4*)&bias[lane * 4];
  float4 o;
  o.x = fmaxf(fmaf(dv, ax, bb.x), 0.f);
  o.y = fmaxf(fmaf(dv, ay, bb.y), 0.f);
  o.z = fmaxf(fmaf(dv, az, bb.z), 0.f);
  o.w = fmaxf(fmaf(dv, aw, bb.w), 0.f);
  ((float4*)outp)[(size_t)v * 16 + lane] = o;
}

// ---------------- GEMM (layer 2): G16 = fp16(dis * (A @ W)), K=64 ----------------

template<int K>
__global__ __launch_bounds__(256) void k_gemm_scaled(const float* __restrict__ X,
                                                     const float* __restrict__ W,
                                                     const float* __restrict__ dis,
                                                     __half* __restrict__ G16, int n) {
  __shared__ float Wl[64 * 64];
  __shared__ float Xl[64 * 64];
  const int tid = threadIdx.x;
  const int row0 = blockIdx.x * 64;
  const int tc = tid & 15;
  const int tr = tid >> 4;
  float acc[4][4] = {};

  for (int k0 = 0; k0 < K; k0 += 64) {
    __syncthreads();
#pragma unroll
    for (int i = 0; i < 4; ++i) {
      int idx = tid * 4 + i * 1024;
      int kr = idx >> 6, c = idx & 63;
      *(vf4*)&Wl[idx] = *(const vf4*)&W[(size_t)(k0 + kr) * 64 + c];
    }
#pragma unroll
    for (int i = 0; i < 4; ++i) {
      int idx = tid * 4 + i * 1024;
      int r = idx >> 6, c = idx & 63;
      int row = row0 + r;
      vf4 v = {0.f, 0.f, 0.f, 0.f};
      if (row < n) v = __builtin_nontemporal_load((const vf4*)&X[(size_t)row * K + k0 + c]);
      *(vf4*)&Xl[idx] = v;
    }
    __syncthreads();
#pragma unroll 4
    for (int kk = 0; kk < 64; kk += 4) {
      float4 xv[4], wv[4];
#pragma unroll
      for (int r = 0; r < 4; ++r) xv[r] = *(float4*)&Xl[(tr * 4 + r) * 64 + kk];
#pragma unroll
      for (int q = 0; q < 4; ++q) wv[q] = *(float4*)&Wl[(kk + q) * 64 + tc * 4];
#pragma unroll
      for (int r = 0; r < 4; ++r) {
        const float xr[4] = {xv[r].x, xv[r].y, xv[r].z, xv[r].w};
#pragma unroll
        for (int q = 0; q < 4; ++q) {
          acc[r][0] += xr[q] * wv[q].x;
          acc[r][1] += xr[q] * wv[q].y;
          acc[r][2] += xr[q] * wv[q].z;
          acc[r][3] += xr[q] * wv[q].w;
        }
      }
    }
  }
#pragma unroll
  for (int r = 0; r < 4; ++r) {
    int row = row0 + tr * 4 + r;
    if (row < n) {
      float s = dis[row];
      __half2 h01 = __floats2half2_rn(acc[r][0] * s, acc[r][1] * s);
      __half2 h23 = __floats2half2_rn(acc[r][2] * s, acc[r][3] * s);
      uint2 st;
      st.x = *reinterpret_cast<unsigned*>(&h01);
      st.y = *reinterpret_cast<unsigned*>(&h23);
      ((uint2*)G16)[(size_t)row * 16 + tc] = st;
    }
  }
}

// ---------------- layer-2 agg (messages pre-scaled): out = relu(dv*(sum g[s] + g[v]) + b) ----------------

__global__ __launch_bounds__(256) void k_agg_csr(const int2* __restrict__ rowrange,
                                                 const int* __restrict__ srcs,
                                                 const __half* __restrict__ g16,
                                                 const float* __restrict__ dis,
                                                 const float* __restrict__ bias,
                                                 float* __restrict__ outp, int n) {
  int v = blockIdx.x * 16 + (threadIdx.x >> 4);
  if (v >= n) return;
  int lane = threadIdx.x & 15;
  int2 rr = rowrange[v];
  int j = rr.x, end = rr.x + rr.y;
  const uint2* g2 = (const uint2*)g16;

  uint2 su = g2[(size_t)v * 16 + lane];
  float2 f0 = __half22float2(*reinterpret_cast<__half2*>(&su.x));
  float2 f1 = __half22float2(*reinterpret_cast<__half2*>(&su.y));
  float ax = f0.x, ay = f0.y, az = f1.x, aw = f1.y;

  for (; j + 8 <= end; j += 8) {
    int s[8];
#pragma unroll
    for (int q = 0; q < 8; ++q) s[q] = __builtin_nontemporal_load(&srcs[j + q]);
    uint2 a[8];
#pragma unroll
    for (int q = 0; q < 8; ++q) a[q] = g2[(size_t)s[q] * 16 + lane];
#pragma unroll
    for (int q = 0; q < 8; ++q) {
      float2 p0 = __half22float2(*reinterpret_cast<__half2*>(&a[q].x));
      float2 p1 = __half22float2(*reinterpret_cast<__half2*>(&a[q].y));
      ax += p0.x; ay += p0.y; az += p1.x; aw += p1.y;
    }
  }
  for (; j < end; ++j) {
    int s0 = __builtin_nontemporal_load(&srcs[j]);
    uint2 a0 = g2[(size_t)s0 * 16 + lane];
    float2 p0 = __half22float2(*reinterpret_cast<__half2*>(&a0.x));
    float2 p1 = __half22float2(*reinterpret_cast<__half2*>(&a0.y));
    ax += p0.x; ay += p0.y; az += p1.x; aw += p1.y;
  }

  float dv = dis[v];
  float4 bb = *(const float4*)&bias[lane * 4];
  float4 o;
  o.x = fmaxf(fmaf(dv, ax, bb.x), 0.f);
  o.y = fmaxf(fmaf(dv, ay, bb.y), 0.f);
  o.z = fmaxf(fmaf(dv, az, bb.z), 0.f);
  o.w = fmaxf(fmaf(dv, aw, bb.w), 0.f);
  ((float4*)outp)[(size_t)v * 16 + lane] = o;
}

// ---------------- final FC ----------------

__global__ __launch_bounds__(256) void k_fc(const float* __restrict__ A,
                                            const float* __restrict__ Wfc,
                                            const float* __restrict__ bfc,
                                            float* __restrict__ outp, int n) {
  __shared__ float Wl[64 * NCLS];
  __shared__ float bl[8];
  int tid = threadIdx.x;
  for (int i = tid; i < 64 * NCLS; i += 256) Wl[i] = Wfc[i];
  if (tid < NCLS) bl[tid] = bfc[tid];
  __syncthreads();
  int row = blockIdx.x * 256 + tid;
  if (row >= n) return;
  float accv[NCLS];
#pragma unroll
  for (int j = 0; j < NCLS; ++j) accv[j] = bl[j];
  const vf4* a4 = (const vf4*)&A[(size_t)row * 64];
#pragma unroll
  for (int k4 = 0; k4 < 16; ++k4) {
    vf4 a = __builtin_nontemporal_load(&a4[k4]);
    const float av[4] = {a.x, a.y, a.z, a.w};
#pragma unroll
    for (int q = 0; q < 4; ++q)
#pragma unroll
      for (int j = 0; j < NCLS; ++j) accv[j] += av[q] * Wl[(k4 * 4 + q) * NCLS + j];
  }
#pragma unroll
  for (int j = 0; j < NCLS; ++j) outp[(size_t)row * NCLS + j] = accv[j];
}

// ---------------- launch ----------------

extern "C" void kernel_launch(void* const* d_in, const int* in_sizes, int n_in,
                              void* d_out, int out_size, void* d_ws, size_t ws_size,
                              hipStream_t stream) {
  const float* x   = (const float*)d_in[0];
  const int*   ei  = (const int*)d_in[1];
  const float* W1  = (const float*)d_in[2];
  const float* b1  = (const float*)d_in[3];
  const float* W2  = (const float*)d_in[4];
  const float* b2  = (const float*)d_in[5];
  const float* Wfc = (const float*)d_in[6];
  const float* bfc = (const float*)d_in[7];
  float* out = (float*)d_out;

  const int n = in_sizes[0] / NFEAT;   // 100000
  const int E = in_sizes[1] / 2;       // 3200000
  const int* src = ei;
  const int* dst = ei + E;
  const int nbuck = (n + 63) >> 6;     // 1563 (<= NBMX)
  const int nbb = (E + CHUNK - 1) / CHUNK;  // 196 binpack blocks
  const int ntile = (n + 63) / 64;     // 1563 gemm tiles

  char* ws = (char*)d_ws;
  size_t off = 0;
  auto alloc = [&](size_t bytes) -> void* {
    void* p = (void*)(ws + off);
    off += (bytes + 255) & ~(size_t)255;
    return p;
  };
  float* dis      = (float*)alloc((size_t)n * 4);
  int2*  rowrange = (int2*)alloc((size_t)n * 8);
  int*   gcur     = (int*)alloc((size_t)nbuck * 4);
  unsigned* packed = (unsigned*)alloc((size_t)nbuck * CAP * 4);  // 25.6MB; becomes srcs in place
  __half* bufA16  = (__half*)alloc((size_t)n * HID * 2);         // 12.8MB (separate: fused overlap)
  float* bufB     = (float*)alloc((size_t)n * HID * 4);          // 25.6MB

  // ---- build chain || gemm1 ----
  k_zero_int<<<(nbuck + 255) / 256, 256, 0, stream>>>(gcur, nbuck);
  k_fused<<<nbb + ntile, 256, FUSED_LDS, stream>>>(src, dst, gcur, packed, E, nbuck, nbb,
                                                   x, W1, bufA16, n);
  k_build<<<nbuck, 256, 0, stream>>>(packed, gcur, rowrange, dis, n, nbuck);

  // ---- layer 1 aggregation (dis-weighted) ----
  k_agg_w<<<(n + 15) / 16, 256, 0, stream>>>(rowrange, (const int*)packed, bufA16, dis, b1, bufB, n);

  // ---- layer 2 ----
  k_gemm_scaled<HID><<<(n + 63) / 64, 256, 0, stream>>>(bufB, W2, dis, bufA16, n);
  k_agg_csr<<<(n + 15) / 16, 256, 0, stream>>>(rowrange, (const int*)packed, bufA16, dis, b2, bufB, n);

  // ---- FC head ----
  k_fc<<<(n + 255) / 256, 256, 0, stream>>>(bufB, Wfc, bfc, out, n);
}